// Round 5
// baseline (3720.422 us; speedup 1.0000x reference)
//
#include <hip/hip_runtime.h>
#include <cstdint>
#include <cstddef>

// Problem constants
#define BB 8
#define LL 512
#define DD 256
#define HH 8
#define DHD 64
#define NLAYER 16
#define HDH 512   // H*DH
#define IN2 2048  // 2*INNER
#define IN1 1024  // INNER

typedef __attribute__((ext_vector_type(8))) short short8;     // 8 x bf16 (mfma A/B frag)
typedef __attribute__((ext_vector_type(4))) float floatx4;    // mfma C/D frag
typedef __attribute__((ext_vector_type(4))) unsigned short ushort4v;
typedef unsigned short u16;

__device__ __forceinline__ floatx4 mfma16(short8 a, short8 b, floatx4 c) {
  return __builtin_amdgcn_mfma_f32_16x16x32_bf16(a, b, c, 0, 0, 0);
}

__device__ __forceinline__ u16 f2b(float f) {
  union { float f; unsigned u; } x; x.f = f;
  unsigned u = x.u + 0x7fffu + ((x.u >> 16) & 1u);  // RNE
  return (u16)(u >> 16);
}

__device__ __forceinline__ float wave_sum(float s) {
#pragma unroll
  for (int off = 32; off; off >>= 1) s += __shfl_xor(s, off);
  return s;
}

// ---- async global->LDS (16B/lane), XOR-swizzled tiles (64-elem rows) ----------
__device__ __forceinline__ void gload_lds16(const u16* g, u16* l) {
  __builtin_amdgcn_global_load_lds((__attribute__((address_space(1))) void*)g,
                                   (__attribute__((address_space(3))) void*)l,
                                   16, 0, 0);
}

// 512-thread stager; NSLOTS = rows*8 (64-elem rows, XOR swizzle).
// Tail handled wave-complete (sbase < NSLOTS is wave-uniform).
template <int NSLOTS>
__device__ __forceinline__ void stage512(const u16* __restrict__ g, int rowstride,
                                         u16* lds, int tid) {
  int wave = tid >> 6, lane = tid & 63;
#pragma unroll
  for (int j = 0; j < (NSLOTS + 511) / 512; ++j) {
    int sbase = j * 512 + wave * 64;
    if (sbase < NSLOTS) {
      int slot = sbase + lane;
      int row = slot >> 3;
      int kg = (slot & 7) ^ (row & 7);
      gload_lds16(g + (size_t)row * rowstride + kg * 8, lds + sbase * 8);
    }
  }
}

__device__ __forceinline__ short8 ld_frag(const u16* T, int row, int kg) {
  return *(const short8*)&T[(row << 6) + (((kg ^ row) & 7) << 3)];
}

// ---------------- device-wide barrier (monotonic counter + generation) --------
// bar[0] = arrival counter (monotonic), bar[1] = generation. Reset by embed
// kernel each graph iteration. Sound under any arrival order; no reset races.
__device__ __forceinline__ void gsync(unsigned* bar, unsigned& syncno) {
  __syncthreads();  // compiler drains vm+lgkm here (full drain) -> LDS safe
  if (threadIdx.x == 0) {
    __threadfence();                       // release phase writes (device scope)
    unsigned my = ++syncno;
    unsigned n = atomicAdd(&bar[0], 1u) + 1u;
    if (n == my * 256u) {
      atomicExch(&bar[1], my);             // last arriver publishes generation
    } else {
      while (atomicAdd(&bar[1], 0u) < my) __builtin_amdgcn_s_sleep(2);
    }
    __threadfence();                       // acquire
  }
  __syncthreads();
}

// ---------------- fused embed + prenorm-LN + layer0 ln1 (+bar reset) ----------
__device__ __forceinline__ float4 ln_math(const float* __restrict__ x,
                                          const float* __restrict__ g,
                                          const float* __restrict__ b, int t) {
  float4 v = *(const float4*)(x + t * 4);
  float s = wave_sum(v.x + v.y + v.z + v.w);
  float mu = s * (1.0f / DD);
  float dx = v.x - mu, dy = v.y - mu, dz = v.z - mu, dw = v.w - mu;
  float ss = wave_sum(dx * dx + dy * dy + dz * dz + dw * dw);
  float r = rsqrtf(ss * (1.0f / DD) + 1e-5f);
  float4 gg = *(const float4*)(g + t * 4);
  float4 bb = *(const float4*)(b + t * 4);
  float4 o;
  o.x = dx * r * gg.x + bb.x;
  o.y = dy * r * gg.y + bb.y;
  o.z = dz * r * gg.z + bb.z;
  o.w = dw * r * gg.w + bb.w;
  return o;
}

__global__ __launch_bounds__(256) void embed_ln_kernel(
    const int* __restrict__ seq, const float* __restrict__ emb,
    const float* __restrict__ png, const float* __restrict__ pnb,
    const float* __restrict__ g1, const float* __restrict__ b1,
    float* __restrict__ X, u16* __restrict__ H, unsigned* bar) {
  if (blockIdx.x == 0 && threadIdx.x == 0) { bar[0] = 0u; bar[1] = 0u; }
  int row = blockIdx.x * 4 + (threadIdx.x >> 6), t = threadIdx.x & 63;
  int tok = seq[row];
  float4 o = ln_math(emb + (size_t)tok * DD, png, pnb, t);
  *(float4*)(X + (size_t)row * DD + t * 4) = o;
  float s = wave_sum(o.x + o.y + o.z + o.w);
  float mu = s * (1.0f / DD);
  float dx = o.x - mu, dy = o.y - mu, dz = o.z - mu, dw = o.w - mu;
  float ss = wave_sum(dx * dx + dy * dy + dz * dz + dw * dw);
  float r = rsqrtf(ss * (1.0f / DD) + 1e-5f);
  float4 gg = *(const float4*)(g1 + t * 4);
  float4 bb = *(const float4*)(b1 + t * 4);
  ushort4v o4;
  o4[0] = f2b(dx * r * gg.x + bb.x);
  o4[1] = f2b(dy * r * gg.y + bb.y);
  o4[2] = f2b(dz * r * gg.z + bb.z);
  o4[3] = f2b(dw * r * gg.w + bb.w);
  *(ushort4v*)(H + (size_t)row * DD + t * 4) = o4;
}

// ---------------- weight transpose+convert for ALL layers (one dispatch) ----------
#define WBUF_LAYER 1310720
__global__ __launch_bounds__(256) void prep_weights_kernel(
    const float* __restrict__ Wq, const float* __restrict__ Wk,
    const float* __restrict__ Wv, const float* __restrict__ Wo,
    const float* __restrict__ W1, const float* __restrict__ W2,
    u16* __restrict__ wbuf_all) {
  __shared__ float tile[32][33];
  int l = blockIdx.x / 1280;
  int bx = blockIdx.x % 1280;
  int tid = threadIdx.x;
  const float* wq = Wq + (size_t)l * DD * HDH;
  const float* wk = Wk + (size_t)l * DD * HDH;
  const float* wv = Wv + (size_t)l * DD * HDH;
  const float* wo = Wo + (size_t)l * HDH * DD;
  const float* w1 = W1 + (size_t)l * DD * IN2;
  const float* w2 = W2 + (size_t)l * IN1 * DD;
  u16* wbuf = wbuf_all + (size_t)l * WBUF_LAYER;

  const float* src; int srcld; u16* dst; int dstld; int dn0, k0, scol0;
  int packW1 = 0;
  if (bx < 384) {
    int t = bx; dn0 = (t % 48) * 32; k0 = (t / 48) * 32;
    scol0 = dn0 & 511;
    src = (dn0 < 512) ? wq : ((dn0 < 1024) ? wk : wv);
    srcld = 512; dst = wbuf; dstld = 256;
  } else if (bx < 512) {
    int t = bx - 384; dn0 = (t % 8) * 32; k0 = (t / 8) * 32; scol0 = dn0;
    src = wo; srcld = 256; dst = wbuf + 393216; dstld = 512;
  } else if (bx < 1024) {
    int t = bx - 512; dn0 = (t % 64) * 32; k0 = (t / 64) * 32; scol0 = dn0;
    src = w1; srcld = 2048; dst = wbuf + 524288; dstld = 256; packW1 = 1;
  } else {
    int t = bx - 1024; dn0 = (t % 8) * 32; k0 = (t / 8) * 32; scol0 = dn0;
    src = w2; srcld = 256; dst = wbuf + 1048576; dstld = 1024;
  }
  int r = tid >> 3, c4 = (tid & 7) * 4;
  float4 v = *(const float4*)&src[(size_t)(k0 + r) * srcld + scol0 + c4];
  tile[r][c4 + 0] = v.x; tile[r][c4 + 1] = v.y;
  tile[r][c4 + 2] = v.z; tile[r][c4 + 3] = v.w;
  __syncthreads();
  int n = tid >> 3, kk = (tid & 7) * 4;
  int drow = dn0 + n;
  if (packW1) {
    if (drow < 1024) drow = ((drow >> 4) << 5) | (drow & 15);
    else { int nn = drow - 1024; drow = (((nn >> 4) << 5) + 16) | (nn & 15); }
  }
  ushort4v o4;
  o4[0] = f2b(tile[kk + 0][n]); o4[1] = f2b(tile[kk + 1][n]);
  o4[2] = f2b(tile[kk + 2][n]); o4[3] = f2b(tile[kk + 3][n]);
  *(ushort4v*)&dst[(size_t)drow * dstld + k0 + kk] = o4;
}

// =================== persistent mega-kernel phases (256 blk x 512 thr) ========
// Shared scratch: 34816 u16 = 68 KB (max over phases; 2 blocks/CU co-residable)

// ---- QKV phase: 128x96 tiles, 8 waves (4x2), 2 reps/block -------------------
__device__ __forceinline__ void phase_qkv(
    const u16* __restrict__ A, const u16* __restrict__ BT,
    u16* __restrict__ qk, u16* __restrict__ vT, u16* smem) {
  u16* Asb[2] = {smem, smem + 8192};
  u16* Bsb[2] = {smem + 16384, smem + 22528};
  int tid = threadIdx.x;
  int wave = tid >> 6, lane = tid & 63;
  int lm = lane & 15, quad = lane >> 4;
  int wr = wave >> 1, wc = wave & 1;   // wr 0..3 (32 rows), wc 0..1 (48 cols)
  int m0 = ((int)blockIdx.x >> 3) * 128;
  const u16* Ab = A + (size_t)m0 * DD;
#pragma unroll 1
  for (int rep = 0; rep < 2; ++rep) {
    int n0 = (((int)blockIdx.x & 7) * 2 + rep) * 96;
    const u16* Bb = BT + (size_t)n0 * DD;
    floatx4 acc[2][3];
#pragma unroll
    for (int mf = 0; mf < 2; ++mf)
#pragma unroll
      for (int nf = 0; nf < 3; ++nf)
#pragma unroll
        for (int r = 0; r < 4; ++r) acc[mf][nf][r] = 0.0f;

    stage512<1024>(Ab, DD, Asb[0], tid);
    stage512<768>(Bb, DD, Bsb[0], tid);
#pragma unroll
    for (int it = 0; it < 4; ++it) {
      if (it < 3) {
        stage512<1024>(Ab + (it + 1) * 64, DD, Asb[(it + 1) & 1], tid);
        stage512<768>(Bb + (it + 1) * 64, DD, Bsb[(it + 1) & 1], tid);
        // per-wave issue: waves0-3 = 2A+2B = 4, waves4-7 = 2A+1B = 3
        if (wave < 4) asm volatile("s_waitcnt vmcnt(4)" ::: "memory");
        else          asm volatile("s_waitcnt vmcnt(3)" ::: "memory");
      } else {
        asm volatile("s_waitcnt vmcnt(0)" ::: "memory");
      }
      __builtin_amdgcn_s_barrier();
      __builtin_amdgcn_sched_barrier(0);
      const u16* Ac = Asb[it & 1];
      const u16* Bc = Bsb[it & 1];
#pragma unroll
      for (int kc = 0; kc < 2; ++kc) {
        short8 af[2], bf[3];
#pragma unroll
        for (int mf = 0; mf < 2; ++mf)
          af[mf] = ld_frag(Ac, wr * 32 + mf * 16 + lm, kc * 4 + quad);
#pragma unroll
        for (int nf = 0; nf < 3; ++nf)
          bf[nf] = ld_frag(Bc, wc * 48 + nf * 16 + lm, kc * 4 + quad);
#pragma unroll
        for (int mf = 0; mf < 2; ++mf)
#pragma unroll
          for (int nf = 0; nf < 3; ++nf)
            acc[mf][nf] = mfma16(af[mf], bf[nf], acc[mf][nf]);
      }
      if (it < 3) {
        asm volatile("s_waitcnt lgkmcnt(0)" ::: "memory");
        __builtin_amdgcn_sched_barrier(0);
        __builtin_amdgcn_s_barrier();
      }
    }
#pragma unroll
    for (int mf = 0; mf < 2; ++mf)
#pragma unroll
      for (int nf = 0; nf < 3; ++nf) {
        int colf = n0 + wc * 48 + nf * 16;
        if (colf < 1024) {
#pragma unroll
          for (int r = 0; r < 4; ++r) {
            int row = m0 + wr * 32 + mf * 16 + quad * 4 + r;
            qk[(size_t)row * 1024 + colf + lm] = f2b(acc[mf][nf][r]);
          }
        } else {
          int token0 = m0 + wr * 32 + mf * 16 + quad * 4;
          int hd = colf + lm - 1024;
          int b = token0 >> 9, key = token0 & 511;
          ushort4v p4;
#pragma unroll
          for (int r = 0; r < 4; ++r) p4[r] = f2b(acc[mf][nf][r]);
          *(ushort4v*)&vT[((size_t)(b * 8 + (hd >> 6)) * 64 + (hd & 63)) * 512 + key] = p4;
        }
      }
    __syncthreads();  // LDS reuse hazard between reps
  }
}

// ---- FFN1 phase: 128x128 tiles + GeGLU, 8 waves (4x2), 2 reps/block ---------
__device__ __forceinline__ void phase_ffn1(
    const u16* __restrict__ A, const u16* __restrict__ BTp,
    const float* __restrict__ b1, u16* __restrict__ G, u16* smem) {
  u16* Asb[2] = {smem, smem + 8192};
  u16* Bsb[2] = {smem + 16384, smem + 24576};
  int tid = threadIdx.x;
  int wave = tid >> 6, lane = tid & 63;
  int lm = lane & 15, quad = lane >> 4;
  int wr = wave >> 1, wc = wave & 1;   // wr 0..3 (32 rows), wc 0..1 (64 cols)
  int m0 = ((int)blockIdx.x >> 3) * 128;
  const u16* Ab = A + (size_t)m0 * DD;
#pragma unroll 1
  for (int rep = 0; rep < 2; ++rep) {
    int n0 = (((int)blockIdx.x & 7) * 2 + rep) * 128;
    const u16* Bb = BTp + (size_t)n0 * DD;
    floatx4 acc[2][4];
#pragma unroll
    for (int mf = 0; mf < 2; ++mf)
#pragma unroll
      for (int nf = 0; nf < 4; ++nf)
#pragma unroll
        for (int r = 0; r < 4; ++r) acc[mf][nf][r] = 0.0f;

    stage512<1024>(Ab, DD, Asb[0], tid);
    stage512<1024>(Bb, DD, Bsb[0], tid);
#pragma unroll
    for (int it = 0; it < 4; ++it) {
      if (it < 3) {
        stage512<1024>(Ab + (it + 1) * 64, DD, Asb[(it + 1) & 1], tid);
        stage512<1024>(Bb + (it + 1) * 64, DD, Bsb[(it + 1) & 1], tid);
        asm volatile("s_waitcnt vmcnt(4)" ::: "memory");  // 2A+2B per wave
      } else {
        asm volatile("s_waitcnt vmcnt(0)" ::: "memory");
      }
      __builtin_amdgcn_s_barrier();
      __builtin_amdgcn_sched_barrier(0);
      const u16* Ac = Asb[it & 1];
      const u16* Bc = Bsb[it & 1];
#pragma unroll
      for (int kc = 0; kc < 2; ++kc) {
        short8 af[2], bf[4];
#pragma unroll
        for (int mf = 0; mf < 2; ++mf)
          af[mf] = ld_frag(Ac, wr * 32 + mf * 16 + lm, kc * 4 + quad);
#pragma unroll
        for (int nf = 0; nf < 4; ++nf)
          bf[nf] = ld_frag(Bc, wc * 64 + nf * 16 + lm, kc * 4 + quad);
#pragma unroll
        for (int mf = 0; mf < 2; ++mf)
#pragma unroll
          for (int nf = 0; nf < 4; ++nf)
            acc[mf][nf] = mfma16(af[mf], bf[nf], acc[mf][nf]);
      }
      if (it < 3) {
        asm volatile("s_waitcnt lgkmcnt(0)" ::: "memory");
        __builtin_amdgcn_sched_barrier(0);
        __builtin_amdgcn_s_barrier();
      }
    }
    int p0 = (n0 + wc * 64) >> 5;
#pragma unroll
    for (int j = 0; j < 2; ++j) {
      int gcol = (p0 + j) * 16 + lm;
      float bv = b1[gcol], bg = b1[1024 + gcol];
#pragma unroll
      for (int mf = 0; mf < 2; ++mf)
#pragma unroll
        for (int r = 0; r < 4; ++r) {
          int row = m0 + wr * 32 + mf * 16 + quad * 4 + r;
          float val = acc[mf][2 * j][r] + bv;
          float gate = acc[mf][2 * j + 1][r] + bg;
          float ge = 0.5f * gate * (1.0f + erff(gate * 0.70710678118654752440f));
          G[(size_t)row * IN1 + gcol] = f2b(val * ge);
        }
    }
    __syncthreads();  // LDS reuse hazard between reps
  }
}

// ---- row GEMM + residual + LN phase: 16x256, BK=64, T4 counted schedule -----
__device__ __forceinline__ void phase_rowln(
    const u16* __restrict__ A, int lda, const u16* __restrict__ BT, int K,
    const float* __restrict__ bias, float* __restrict__ X,
    const float* __restrict__ lng, const float* __restrict__ lnb,
    u16* __restrict__ Hout,
    const float* __restrict__ Wout, const float* __restrict__ bout,
    float* __restrict__ outp, u16* smem) {
  u16* Asb[2] = {smem, smem + 1024};
  u16* Bsb[2] = {smem + 2048, smem + 18432};
  int tid = threadIdx.x;
  int wave = tid >> 6, lane = tid & 63;
  int lm = lane & 15, quad = lane >> 4;
  int m0 = (int)blockIdx.x * 16;

  floatx4 acc[2];
#pragma unroll
  for (int nf = 0; nf < 2; ++nf)
#pragma unroll
    for (int r = 0; r < 4; ++r) acc[nf][r] = 0.0f;

  const u16* Ab = A + (size_t)m0 * lda;

  // early residual prefetch (oldest vmem ops; counted waits below account for them)
  float xres[2][4];
#pragma unroll
  for (int nf = 0; nf < 2; ++nf)
#pragma unroll
    for (int r = 0; r < 4; ++r)
      xres[nf][r] =
          X[(size_t)(m0 + quad * 4 + r) * DD + wave * 32 + nf * 16 + lm];

  auto stageA = [&](int k0, u16* dst) {
    if (tid < 128) {  // 128 slots (16 rows x 8 groups), waves 0-1: 1 load
      int sbase = wave * 64;
      int slot = sbase + lane;
      int row = slot >> 3;
      int kg = (slot & 7) ^ (row & 7);
      gload_lds16(Ab + (size_t)row * lda + k0 + kg * 8, dst + sbase * 8);
    }
  };
  auto stageB = [&](int k0, u16* dst) {
#pragma unroll
    for (int j = 0; j < 4; ++j) {  // 2048 slots / 512 thr: 4 loads/wave
      int sbase = j * 512 + wave * 64;
      int slot = sbase + lane;
      int row = slot >> 3;
      int kg = (slot & 7) ^ (row & 7);
      gload_lds16(BT + (size_t)row * K + k0 + kg * 8, dst + sbase * 8);
    }
  };

  stageA(0, Asb[0]);
  stageB(0, Bsb[0]);
  int iters = K >> 6;
#pragma unroll 1
  for (int it = 0; it < iters; ++it) {
    if (it + 1 < iters) {
      stageA((it + 1) * 64, Asb[(it + 1) & 1]);
      stageB((it + 1) * 64, Bsb[(it + 1) & 1]);
      // waves0-1 issue 5/stage, waves2-7 issue 4/stage
      if (wave < 2) asm volatile("s_waitcnt vmcnt(5)" ::: "memory");
      else          asm volatile("s_waitcnt vmcnt(4)" ::: "memory");
    } else {
      asm volatile("s_waitcnt vmcnt(0)" ::: "memory");
    }
    __builtin_amdgcn_s_barrier();
    __builtin_amdgcn_sched_barrier(0);
    const u16* Ac = Asb[it & 1];
    const u16* Bc = Bsb[it & 1];
#pragma unroll
    for (int kc = 0; kc < 2; ++kc) {
      short8 af = ld_frag(Ac, lm, kc * 4 + quad);
#pragma unroll
      for (int nf = 0; nf < 2; ++nf) {
        short8 bf = ld_frag(Bc, wave * 32 + nf * 16 + lm, kc * 4 + quad);
        acc[nf] = mfma16(af, bf, acc[nf]);
      }
    }
    asm volatile("s_waitcnt lgkmcnt(0)" ::: "memory");
    __builtin_amdgcn_sched_barrier(0);
    __builtin_amdgcn_s_barrier();
  }
  // epilogue: residual into X and LDS (xs = Bsb[0], 16 KB of 32 KB region)
  float* xs = (float*)Bsb[0];
#pragma unroll
  for (int nf = 0; nf < 2; ++nf) {
    int col = wave * 32 + nf * 16 + lm;
    float bv = bias ? bias[col] : 0.0f;
#pragma unroll
    for (int r = 0; r < 4; ++r) {
      int row = quad * 4 + r;
      float v = acc[nf][r] + bv + xres[nf][r];
      X[(size_t)(m0 + row) * DD + col] = v;
      xs[row * DD + col] = v;
    }
  }
  __syncthreads();
  float4 gg = *(const float4*)(lng + lane * 4);
  float4 bb = *(const float4*)(lnb + lane * 4);
#pragma unroll
  for (int rr = 0; rr < 2; ++rr) {
    int row = wave * 2 + rr;
    float4 v = *(const float4*)&xs[row * DD + lane * 4];
    float s = wave_sum(v.x + v.y + v.z + v.w);
    float mu = s * (1.0f / DD);
    float dx = v.x - mu, dy = v.y - mu, dz = v.z - mu, dw = v.w - mu;
    float ss = wave_sum(dx * dx + dy * dy + dz * dz + dw * dw);
    float rc = rsqrtf(ss * (1.0f / DD) + 1e-5f);
    float o0 = dx * rc * gg.x + bb.x;
    float o1 = dy * rc * gg.y + bb.y;
    float o2 = dz * rc * gg.z + bb.z;
    float o3 = dw * rc * gg.w + bb.w;
    ushort4v o4;
    o4[0] = f2b(o0); o4[1] = f2b(o1); o4[2] = f2b(o2); o4[3] = f2b(o3);
    *(ushort4v*)(Hout + (size_t)(m0 + row) * DD + lane * 4) = o4;
    if (Wout) {  // final layer: fused output projection (256 -> 2)
      int d0 = lane * 4;
      float s0 = o0 * Wout[d0 * 2] + o1 * Wout[(d0 + 1) * 2] +
                 o2 * Wout[(d0 + 2) * 2] + o3 * Wout[(d0 + 3) * 2];
      float s1 = o0 * Wout[d0 * 2 + 1] + o1 * Wout[(d0 + 1) * 2 + 1] +
                 o2 * Wout[(d0 + 2) * 2 + 1] + o3 * Wout[(d0 + 3) * 2 + 1];
      s0 = wave_sum(s0);
      s1 = wave_sum(s1);
      if (lane == 0) {
        outp[(size_t)(m0 + row) * 2 + 0] = s0 + bout[0];
        outp[(size_t)(m0 + row) * 2 + 1] = s1 + bout[1];
      }
    }
  }
  __syncthreads();
}

// ---- attention phase: flash, 128 q rows/block, 8 waves ----------------------
__device__ __forceinline__ void phase_attn(
    const u16* __restrict__ qk, const u16* __restrict__ vT,
    const int* __restrict__ mask_raw, u16* __restrict__ O, u16* smem) {
  u16* Ksb[2] = {smem, smem + 4096};
  u16* Vsb[2] = {smem + 8192, smem + 12288};
  u16* Ps = smem + 16384;                 // [8][16][72]
  float* madd = (float*)(smem + 25600);   // [64]

  const int tid = threadIdx.x, wave = tid >> 6, lane = tid & 63;
  const int lm = lane & 15, quad = lane >> 4;
  const int bid = blockIdx.x;
  const int qb = bid & 3, h = (bid >> 2) & 7, b = bid >> 5;
  const float slope = exp2f(-(float)(h + 1));

  int w0 = mask_raw[0];
  int mmode = (w0 == 1) ? 0 : ((w0 == 0x3f800000) ? 2 : 1);
  const int krow_base = b * LL;

  int ntv = 8;
#pragma unroll
  for (int t = 7; t >= 0; --t) {
    bool tv;
    int gi = krow_base + t * 64;
    if (mmode == 0) tv = mask_raw[gi] != 0;
    else if (mmode == 1) tv = ((const signed char*)mask_raw)[gi] != 0;
    else tv = ((const float*)mask_raw)[gi] != 0.0f;
    if (!tv) ntv = t;
  }

  const int q0 = qb * 128 + wave * 16;
  const int qg = b * LL + q0;
  const float qpos = (float)(q0 + lm);

  const u16* qp = qk + (size_t)(qg + lm) * 1024 + h * 64 + quad * 8;
  short8 qf0 = *(const short8*)qp;
  short8 qf1 = *(const short8*)(qp + 32);

  floatx4 oc[4];
#pragma unroll
  for (int nf = 0; nf < 4; ++nf)
#pragma unroll
    for (int r = 0; r < 4; ++r) oc[nf][r] = 0.0f;
  float mrow = -1e30f, lrow = 0.0f;

  const u16* kbase_p = qk + (size_t)krow_base * 1024 + 512 + h * 64;
  const u16* vbase = vT + (size_t)(b * 8 + h) * 64 * 512;

  stage512<512>(kbase_p, 1024, Ksb[0], tid);
  stage512<512>(vbase, 512, Vsb[0], tid);
  if (tid < 64) {
    int gi = krow_base + (ntv - 1) * 64 + tid;
    bool valid;
    if (mmode == 0) valid = mask_raw[gi] != 0;
    else if (mmode == 1) valid = ((const signed char*)mask_raw)[gi] != 0;
    else valid = ((const float*)mask_raw)[gi] != 0.0f;
    madd[tid] = valid ? 0.0f : -1e9f;
  }
  __syncthreads();  // madd visible; stage(0) drained

#pragma unroll 1
  for (int t = 0; t < ntv; ++t) {
    int k0 = t * 64;
    if (t + 1 < ntv) {
      stage512<512>(kbase_p + (size_t)(t + 1) * 64 * 1024, 1024,
                    Ksb[(t + 1) & 1], tid);
      stage512<512>(vbase + (t + 1) * 64, 512, Vsb[(t + 1) & 1], tid);
      asm volatile("s_waitcnt vmcnt(2)" ::: "memory");  // stage(t) landed
    } else {
      asm volatile("s_waitcnt vmcnt(0)" ::: "memory");
    }
    __builtin_amdgcn_s_barrier();
    __builtin_amdgcn_sched_barrier(0);
    const u16* Kc = Ksb[t & 1];
    const u16* Vc = Vsb[t & 1];
    bool bnd = (t == ntv - 1);

    float sc[4][4];
    float tmax = -3e38f;
#pragma unroll
    for (int nt = 0; nt < 4; ++nt) {
      floatx4 pc;
#pragma unroll
      for (int r = 0; r < 4; ++r) pc[r] = 0.0f;
      short8 kf0 = ld_frag(Kc, nt * 16 + lm, quad);
      short8 kf1 = ld_frag(Kc, nt * 16 + lm, 4 + quad);
      pc = mfma16(kf0, qf0, pc);
      pc = mfma16(kf1, qf1, pc);
      float kbase = (float)(k0 + nt * 16 + quad * 4);
#pragma unroll
      for (int r = 0; r < 4; ++r) {
        float s = pc[r] * 0.125f - slope * fabsf(qpos - (kbase + r));
        sc[nt][r] = s;
      }
      if (bnd) {
        float4 ma = *(const float4*)&madd[nt * 16 + quad * 4];
#pragma unroll
        for (int r = 0; r < 4; ++r) sc[nt][r] += ((const float*)&ma)[r];
      }
#pragma unroll
      for (int r = 0; r < 4; ++r) tmax = fmaxf(tmax, sc[nt][r]);
    }
    tmax = fmaxf(tmax, __shfl_xor(tmax, 16));
    tmax = fmaxf(tmax, __shfl_xor(tmax, 32));
    float nm = fmaxf(mrow, tmax);
    float alpha = __expf(mrow - nm);
    mrow = nm;
    float rsum = 0.0f;
#pragma unroll
    for (int nt = 0; nt < 4; ++nt)
#pragma unroll
      for (int r = 0; r < 4; ++r) {
        float p = __expf(sc[nt][r] - nm);
        sc[nt][r] = p;
        rsum += p;
      }
    rsum += __shfl_xor(rsum, 16);
    rsum += __shfl_xor(rsum, 32);
    lrow = lrow * alpha + rsum;
    float av[4];
#pragma unroll
    for (int r = 0; r < 4; ++r) av[r] = __shfl(alpha, quad * 4 + r);
#pragma unroll
    for (int nf = 0; nf < 4; ++nf)
#pragma unroll
      for (int r = 0; r < 4; ++r) oc[nf][r] *= av[r];
#pragma unroll
    for (int nt = 0; nt < 4; ++nt) {
      ushort4v p4;
#pragma unroll
      for (int r = 0; r < 4; ++r) p4[r] = f2b(sc[nt][r]);
      *(ushort4v*)&Ps[(wave * 16 + lm) * 72 + nt * 16 + quad * 4] = p4;
    }
#pragma unroll
    for (int kc = 0; kc < 2; ++kc) {
      short8 af = *(const short8*)&Ps[(wave * 16 + lm) * 72 + kc * 32 + quad * 8];
#pragma unroll
      for (int nf = 0; nf < 4; ++nf) {
        short8 bv = ld_frag(Vc, nf * 16 + lm, kc * 4 + quad);
        oc[nf] = mfma16(af, bv, oc[nf]);
      }
    }
    if (t + 2 < ntv) {  // compute(t) reads done before stage(t+2) writes
      asm volatile("s_waitcnt lgkmcnt(0)" ::: "memory");
      __builtin_amdgcn_sched_barrier(0);
      __builtin_amdgcn_s_barrier();
    }
  }
  float rl = 1.0f / lrow;
  float rv[4];
#pragma unroll
  for (int r = 0; r < 4; ++r) rv[r] = __shfl(rl, quad * 4 + r);
#pragma unroll
  for (int nf = 0; nf < 4; ++nf)
#pragma unroll
    for (int r = 0; r < 4; ++r) {
      int qq = qg + quad * 4 + r;
      O[(size_t)qq * HDH + h * 64 + nf * 16 + lm] = f2b(oc[nf][r] * rv[r]);
    }
}

// ---- the persistent layer-stack kernel --------------------------------------
__global__ __launch_bounds__(512, 4) void mega_kernel(
    u16* __restrict__ hb, const u16* __restrict__ wbuf,
    u16* __restrict__ qk, u16* __restrict__ vT,
    u16* __restrict__ obuf, u16* __restrict__ gbuf,
    float* __restrict__ x, const int* __restrict__ mask,
    const float* __restrict__ b1, const float* __restrict__ b2,
    const float* __restrict__ ln1g, const float* __restrict__ ln1b,
    const float* __restrict__ ln2g, const float* __restrict__ ln2b,
    const float* __restrict__ fng, const float* __restrict__ fnb,
    const float* __restrict__ Wout, const float* __restrict__ bout,
    float* __restrict__ out, unsigned* bar) {
  __shared__ __align__(16) u16 smem[34816];  // 68 KB
  unsigned syncno = 0;
#pragma unroll 1
  for (int l = 0; l < NLAYER; ++l) {
    const u16* wl = wbuf + (size_t)l * WBUF_LAYER;

    phase_qkv(hb, wl, qk, vT, smem);
    gsync(bar, syncno);

    phase_attn(qk, vT, mask, obuf, smem);
    gsync(bar, syncno);

    phase_rowln(obuf, HDH, wl + 393216, HDH, nullptr, x,
                ln2g + l * DD, ln2b + l * DD, hb,
                nullptr, nullptr, nullptr, smem);
    gsync(bar, syncno);

    phase_ffn1(hb, wl + 524288, b1 + (size_t)l * IN2, gbuf, smem);
    gsync(bar, syncno);

    const float* ng = (l < NLAYER - 1) ? (ln1g + (l + 1) * DD) : fng;
    const float* nb = (l < NLAYER - 1) ? (ln1b + (l + 1) * DD) : fnb;
    phase_rowln(gbuf, IN1, wl + 1048576, IN1, b2 + (size_t)l * DD, x, ng, nb, hb,
                (l == NLAYER - 1) ? Wout : nullptr,
                (l == NLAYER - 1) ? bout : nullptr,
                (l == NLAYER - 1) ? out : nullptr, smem);
    if (l + 1 < NLAYER) gsync(bar, syncno);
  }
}

extern "C" void kernel_launch(void* const* d_in, const int* in_sizes, int n_in,
                              void* d_out, int out_size, void* d_ws, size_t ws_size,
                              hipStream_t stream) {
  const int* seq = (const int*)d_in[0];
  const int* mask = (const int*)d_in[1];
  const float* emb = (const float*)d_in[2];
  const float* png = (const float*)d_in[3];
  const float* pnb = (const float*)d_in[4];
  const float* ln1g = (const float*)d_in[5];
  const float* ln1b = (const float*)d_in[6];
  const float* Wq = (const float*)d_in[7];
  const float* Wk = (const float*)d_in[8];
  const float* Wv = (const float*)d_in[9];
  const float* Wo = (const float*)d_in[10];
  const float* ln2g = (const float*)d_in[11];
  const float* ln2b = (const float*)d_in[12];
  const float* W1 = (const float*)d_in[13];
  const float* b1 = (const float*)d_in[14];
  const float* W2 = (const float*)d_in[15];
  const float* b2 = (const float*)d_in[16];
  const float* fng = (const float*)d_in[17];
  const float* fnb = (const float*)d_in[18];
  const float* Wout = (const float*)d_in[19];
  const float* bout = (const float*)d_in[20];
  float* out = (float*)d_out;

  uint8_t* wsb = (uint8_t*)d_ws;
  float* x = (float*)(wsb + 0);            //  4 MB
  u16* hb = (u16*)(wsb + 4194304);         //  2 MB
  u16* wbuf = (u16*)(wsb + 6291456);       // 40 MB (all layers)
  u16* qk = (u16*)(wsb + 48234496);        //  8 MB
  u16* vT = (u16*)(wsb + 56623104);        //  4 MB
  u16* obuf = (u16*)(wsb + 60817408);      //  4 MB
  u16* gbuf = (u16*)(wsb + 65011712);      //  8 MB
  unsigned* bar = (unsigned*)(wsb + 73400320);  // 2 u32 barrier state

  const int M = BB * LL;  // 4096

  prep_weights_kernel<<<16 * 1280, 256, 0, stream>>>(Wq, Wk, Wv, Wo, W1, W2, wbuf);
  embed_ln_kernel<<<M / 4, 256, 0, stream>>>(seq, emb, png, pnb, ln1g, ln1b, x, hb, bar);

  mega_kernel<<<256, 512, 0, stream>>>(
      hb, wbuf, qk, vT, obuf, gbuf, x, mask, b1, b2,
      ln1g, ln1b, ln2g, ln2b, fng, fnb, Wout, bout, out, bar);

  (void)in_sizes; (void)n_in; (void)out_size; (void)ws_size;
}

// Round 6
// 3649.077 us; speedup vs baseline: 1.0196x; 1.0196x over previous
//
#include <hip/hip_runtime.h>
#include <cstdint>
#include <cstddef>

// Problem constants
#define BB 8
#define LL 512
#define DD 256
#define HH 8
#define DHD 64
#define NLAYER 16
#define HDH 512   // H*DH
#define IN2 2048  // 2*INNER
#define IN1 1024  // INNER

typedef __attribute__((ext_vector_type(8))) short short8;     // 8 x bf16 (mfma A/B frag)
typedef __attribute__((ext_vector_type(4))) float floatx4;    // mfma C/D frag
typedef __attribute__((ext_vector_type(4))) unsigned short ushort4v;
typedef unsigned short u16;

__device__ __forceinline__ floatx4 mfma16(short8 a, short8 b, floatx4 c) {
  return __builtin_amdgcn_mfma_f32_16x16x32_bf16(a, b, c, 0, 0, 0);
}

__device__ __forceinline__ u16 f2b(float f) {
  union { float f; unsigned u; } x; x.f = f;
  unsigned u = x.u + 0x7fffu + ((x.u >> 16) & 1u);  // RNE
  return (u16)(u >> 16);
}

__device__ __forceinline__ float wave_sum(float s) {
#pragma unroll
  for (int off = 32; off; off >>= 1) s += __shfl_xor(s, off);
  return s;
}

// ---- async global->LDS (16B/lane), XOR-swizzled tiles (64-elem rows) ----------
__device__ __forceinline__ void gload_lds16(const u16* g, u16* l) {
  __builtin_amdgcn_global_load_lds((__attribute__((address_space(1))) void*)g,
                                   (__attribute__((address_space(3))) void*)l,
                                   16, 0, 0);
}

// 512-thread stager; NSLOTS = rows*8 (64-elem rows, XOR swizzle).
// Tail handled wave-complete (sbase < NSLOTS is wave-uniform).
template <int NSLOTS>
__device__ __forceinline__ void stage512(const u16* __restrict__ g, int rowstride,
                                         u16* lds, int tid) {
  int wave = tid >> 6, lane = tid & 63;
#pragma unroll
  for (int j = 0; j < (NSLOTS + 511) / 512; ++j) {
    int sbase = j * 512 + wave * 64;
    if (sbase < NSLOTS) {
      int slot = sbase + lane;
      int row = slot >> 3;
      int kg = (slot & 7) ^ (row & 7);
      gload_lds16(g + (size_t)row * rowstride + kg * 8, lds + sbase * 8);
    }
  }
}

__device__ __forceinline__ short8 ld_frag(const u16* T, int row, int kg) {
  return *(const short8*)&T[(row << 6) + (((kg ^ row) & 7) << 3)];
}

// ---------------- device-wide barrier (monotonic counter + generation) --------
// bar[0] = arrival counter (monotonic), bar[1] = generation. Reset by embed
// kernel each graph iteration.
// r6 fix: poll with relaxed AGENT-scope atomic LOAD (LLC read, no RMW
// serialization / line bouncing) + s_sleep backoff. r5's atomicAdd(,0) poll
// was an RMW storm: ~40 us/barrier, 1.9 GB fetch traffic, 90% idle kernel.
__device__ __forceinline__ void gsync(unsigned* bar, unsigned& syncno) {
  __syncthreads();  // compiler drains vm+lgkm here (full drain) -> LDS safe
  if (threadIdx.x == 0) {
    __threadfence();                       // release phase writes (device scope)
    unsigned my = ++syncno;
    unsigned n = atomicAdd(&bar[0], 1u) + 1u;
    if (n == my * 256u) {
      atomicExch(&bar[1], my);             // last arriver publishes generation
    } else {
      while (__hip_atomic_load(&bar[1], __ATOMIC_RELAXED,
                               __HIP_MEMORY_SCOPE_AGENT) < my)
        __builtin_amdgcn_s_sleep(16);
    }
    __threadfence();                       // acquire
  }
  __syncthreads();
}

// ---------------- fused embed + prenorm-LN + layer0 ln1 (+bar reset) ----------
__device__ __forceinline__ float4 ln_math(const float* __restrict__ x,
                                          const float* __restrict__ g,
                                          const float* __restrict__ b, int t) {
  float4 v = *(const float4*)(x + t * 4);
  float s = wave_sum(v.x + v.y + v.z + v.w);
  float mu = s * (1.0f / DD);
  float dx = v.x - mu, dy = v.y - mu, dz = v.z - mu, dw = v.w - mu;
  float ss = wave_sum(dx * dx + dy * dy + dz * dz + dw * dw);
  float r = rsqrtf(ss * (1.0f / DD) + 1e-5f);
  float4 gg = *(const float4*)(g + t * 4);
  float4 bb = *(const float4*)(b + t * 4);
  float4 o;
  o.x = dx * r * gg.x + bb.x;
  o.y = dy * r * gg.y + bb.y;
  o.z = dz * r * gg.z + bb.z;
  o.w = dw * r * gg.w + bb.w;
  return o;
}

__global__ __launch_bounds__(256) void embed_ln_kernel(
    const int* __restrict__ seq, const float* __restrict__ emb,
    const float* __restrict__ png, const float* __restrict__ pnb,
    const float* __restrict__ g1, const float* __restrict__ b1,
    float* __restrict__ X, u16* __restrict__ H, unsigned* bar) {
  if (blockIdx.x == 0 && threadIdx.x == 0) { bar[0] = 0u; bar[1] = 0u; }
  int row = blockIdx.x * 4 + (threadIdx.x >> 6), t = threadIdx.x & 63;
  int tok = seq[row];
  float4 o = ln_math(emb + (size_t)tok * DD, png, pnb, t);
  *(float4*)(X + (size_t)row * DD + t * 4) = o;
  float s = wave_sum(o.x + o.y + o.z + o.w);
  float mu = s * (1.0f / DD);
  float dx = o.x - mu, dy = o.y - mu, dz = o.z - mu, dw = o.w - mu;
  float ss = wave_sum(dx * dx + dy * dy + dz * dz + dw * dw);
  float r = rsqrtf(ss * (1.0f / DD) + 1e-5f);
  float4 gg = *(const float4*)(g1 + t * 4);
  float4 bb = *(const float4*)(b1 + t * 4);
  ushort4v o4;
  o4[0] = f2b(dx * r * gg.x + bb.x);
  o4[1] = f2b(dy * r * gg.y + bb.y);
  o4[2] = f2b(dz * r * gg.z + bb.z);
  o4[3] = f2b(dw * r * gg.w + bb.w);
  *(ushort4v*)(H + (size_t)row * DD + t * 4) = o4;
}

// ---------------- weight transpose+convert for ALL layers (one dispatch) ----------
#define WBUF_LAYER 1310720
__global__ __launch_bounds__(256) void prep_weights_kernel(
    const float* __restrict__ Wq, const float* __restrict__ Wk,
    const float* __restrict__ Wv, const float* __restrict__ Wo,
    const float* __restrict__ W1, const float* __restrict__ W2,
    u16* __restrict__ wbuf_all) {
  __shared__ float tile[32][33];
  int l = blockIdx.x / 1280;
  int bx = blockIdx.x % 1280;
  int tid = threadIdx.x;
  const float* wq = Wq + (size_t)l * DD * HDH;
  const float* wk = Wk + (size_t)l * DD * HDH;
  const float* wv = Wv + (size_t)l * DD * HDH;
  const float* wo = Wo + (size_t)l * HDH * DD;
  const float* w1 = W1 + (size_t)l * DD * IN2;
  const float* w2 = W2 + (size_t)l * IN1 * DD;
  u16* wbuf = wbuf_all + (size_t)l * WBUF_LAYER;

  const float* src; int srcld; u16* dst; int dstld; int dn0, k0, scol0;
  int packW1 = 0;
  if (bx < 384) {
    int t = bx; dn0 = (t % 48) * 32; k0 = (t / 48) * 32;
    scol0 = dn0 & 511;
    src = (dn0 < 512) ? wq : ((dn0 < 1024) ? wk : wv);
    srcld = 512; dst = wbuf; dstld = 256;
  } else if (bx < 512) {
    int t = bx - 384; dn0 = (t % 8) * 32; k0 = (t / 8) * 32; scol0 = dn0;
    src = wo; srcld = 256; dst = wbuf + 393216; dstld = 512;
  } else if (bx < 1024) {
    int t = bx - 512; dn0 = (t % 64) * 32; k0 = (t / 64) * 32; scol0 = dn0;
    src = w1; srcld = 2048; dst = wbuf + 524288; dstld = 256; packW1 = 1;
  } else {
    int t = bx - 1024; dn0 = (t % 8) * 32; k0 = (t / 8) * 32; scol0 = dn0;
    src = w2; srcld = 256; dst = wbuf + 1048576; dstld = 1024;
  }
  int r = tid >> 3, c4 = (tid & 7) * 4;
  float4 v = *(const float4*)&src[(size_t)(k0 + r) * srcld + scol0 + c4];
  tile[r][c4 + 0] = v.x; tile[r][c4 + 1] = v.y;
  tile[r][c4 + 2] = v.z; tile[r][c4 + 3] = v.w;
  __syncthreads();
  int n = tid >> 3, kk = (tid & 7) * 4;
  int drow = dn0 + n;
  if (packW1) {
    if (drow < 1024) drow = ((drow >> 4) << 5) | (drow & 15);
    else { int nn = drow - 1024; drow = (((nn >> 4) << 5) + 16) | (nn & 15); }
  }
  ushort4v o4;
  o4[0] = f2b(tile[kk + 0][n]); o4[1] = f2b(tile[kk + 1][n]);
  o4[2] = f2b(tile[kk + 2][n]); o4[3] = f2b(tile[kk + 3][n]);
  *(ushort4v*)&dst[(size_t)drow * dstld + k0 + kk] = o4;
}

// =================== persistent mega-kernel phases (256 blk x 512 thr) ========
// Shared scratch: 34816 u16 = 68 KB (max over phases; 2 blocks/CU co-residable)

// ---- QKV phase: 128x96 tiles, 8 waves (4x2), 2 reps/block -------------------
__device__ __forceinline__ void phase_qkv(
    const u16* __restrict__ A, const u16* __restrict__ BT,
    u16* __restrict__ qk, u16* __restrict__ vT, u16* smem) {
  u16* Asb[2] = {smem, smem + 8192};
  u16* Bsb[2] = {smem + 16384, smem + 22528};
  int tid = threadIdx.x;
  int wave = tid >> 6, lane = tid & 63;
  int lm = lane & 15, quad = lane >> 4;
  int wr = wave >> 1, wc = wave & 1;   // wr 0..3 (32 rows), wc 0..1 (48 cols)
  int m0 = ((int)blockIdx.x >> 3) * 128;
  const u16* Ab = A + (size_t)m0 * DD;
#pragma unroll 1
  for (int rep = 0; rep < 2; ++rep) {
    int n0 = (((int)blockIdx.x & 7) * 2 + rep) * 96;
    const u16* Bb = BT + (size_t)n0 * DD;
    floatx4 acc[2][3];
#pragma unroll
    for (int mf = 0; mf < 2; ++mf)
#pragma unroll
      for (int nf = 0; nf < 3; ++nf)
#pragma unroll
        for (int r = 0; r < 4; ++r) acc[mf][nf][r] = 0.0f;

    stage512<1024>(Ab, DD, Asb[0], tid);
    stage512<768>(Bb, DD, Bsb[0], tid);
#pragma unroll
    for (int it = 0; it < 4; ++it) {
      if (it < 3) {
        stage512<1024>(Ab + (it + 1) * 64, DD, Asb[(it + 1) & 1], tid);
        stage512<768>(Bb + (it + 1) * 64, DD, Bsb[(it + 1) & 1], tid);
        // per-wave issue: waves0-3 = 2A+2B = 4, waves4-7 = 2A+1B = 3
        if (wave < 4) asm volatile("s_waitcnt vmcnt(4)" ::: "memory");
        else          asm volatile("s_waitcnt vmcnt(3)" ::: "memory");
      } else {
        asm volatile("s_waitcnt vmcnt(0)" ::: "memory");
      }
      __builtin_amdgcn_s_barrier();
      __builtin_amdgcn_sched_barrier(0);
      const u16* Ac = Asb[it & 1];
      const u16* Bc = Bsb[it & 1];
#pragma unroll
      for (int kc = 0; kc < 2; ++kc) {
        short8 af[2], bf[3];
#pragma unroll
        for (int mf = 0; mf < 2; ++mf)
          af[mf] = ld_frag(Ac, wr * 32 + mf * 16 + lm, kc * 4 + quad);
#pragma unroll
        for (int nf = 0; nf < 3; ++nf)
          bf[nf] = ld_frag(Bc, wc * 48 + nf * 16 + lm, kc * 4 + quad);
#pragma unroll
        for (int mf = 0; mf < 2; ++mf)
#pragma unroll
          for (int nf = 0; nf < 3; ++nf)
            acc[mf][nf] = mfma16(af[mf], bf[nf], acc[mf][nf]);
      }
      if (it < 3) {
        asm volatile("s_waitcnt lgkmcnt(0)" ::: "memory");
        __builtin_amdgcn_sched_barrier(0);
        __builtin_amdgcn_s_barrier();
      }
    }
#pragma unroll
    for (int mf = 0; mf < 2; ++mf)
#pragma unroll
      for (int nf = 0; nf < 3; ++nf) {
        int colf = n0 + wc * 48 + nf * 16;
        if (colf < 1024) {
#pragma unroll
          for (int r = 0; r < 4; ++r) {
            int row = m0 + wr * 32 + mf * 16 + quad * 4 + r;
            qk[(size_t)row * 1024 + colf + lm] = f2b(acc[mf][nf][r]);
          }
        } else {
          int token0 = m0 + wr * 32 + mf * 16 + quad * 4;
          int hd = colf + lm - 1024;
          int b = token0 >> 9, key = token0 & 511;
          ushort4v p4;
#pragma unroll
          for (int r = 0; r < 4; ++r) p4[r] = f2b(acc[mf][nf][r]);
          *(ushort4v*)&vT[((size_t)(b * 8 + (hd >> 6)) * 64 + (hd & 63)) * 512 + key] = p4;
        }
      }
    __syncthreads();  // LDS reuse hazard between reps
  }
}

// ---- FFN1 phase: 128x128 tiles + GeGLU, 8 waves (4x2), 2 reps/block ---------
__device__ __forceinline__ void phase_ffn1(
    const u16* __restrict__ A, const u16* __restrict__ BTp,
    const float* __restrict__ b1, u16* __restrict__ G, u16* smem) {
  u16* Asb[2] = {smem, smem + 8192};
  u16* Bsb[2] = {smem + 16384, smem + 24576};
  int tid = threadIdx.x;
  int wave = tid >> 6, lane = tid & 63;
  int lm = lane & 15, quad = lane >> 4;
  int wr = wave >> 1, wc = wave & 1;   // wr 0..3 (32 rows), wc 0..1 (64 cols)
  int m0 = ((int)blockIdx.x >> 3) * 128;
  const u16* Ab = A + (size_t)m0 * DD;
#pragma unroll 1
  for (int rep = 0; rep < 2; ++rep) {
    int n0 = (((int)blockIdx.x & 7) * 2 + rep) * 128;
    const u16* Bb = BTp + (size_t)n0 * DD;
    floatx4 acc[2][4];
#pragma unroll
    for (int mf = 0; mf < 2; ++mf)
#pragma unroll
      for (int nf = 0; nf < 4; ++nf)
#pragma unroll
        for (int r = 0; r < 4; ++r) acc[mf][nf][r] = 0.0f;

    stage512<1024>(Ab, DD, Asb[0], tid);
    stage512<1024>(Bb, DD, Bsb[0], tid);
#pragma unroll
    for (int it = 0; it < 4; ++it) {
      if (it < 3) {
        stage512<1024>(Ab + (it + 1) * 64, DD, Asb[(it + 1) & 1], tid);
        stage512<1024>(Bb + (it + 1) * 64, DD, Bsb[(it + 1) & 1], tid);
        asm volatile("s_waitcnt vmcnt(4)" ::: "memory");  // 2A+2B per wave
      } else {
        asm volatile("s_waitcnt vmcnt(0)" ::: "memory");
      }
      __builtin_amdgcn_s_barrier();
      __builtin_amdgcn_sched_barrier(0);
      const u16* Ac = Asb[it & 1];
      const u16* Bc = Bsb[it & 1];
#pragma unroll
      for (int kc = 0; kc < 2; ++kc) {
        short8 af[2], bf[4];
#pragma unroll
        for (int mf = 0; mf < 2; ++mf)
          af[mf] = ld_frag(Ac, wr * 32 + mf * 16 + lm, kc * 4 + quad);
#pragma unroll
        for (int nf = 0; nf < 4; ++nf)
          bf[nf] = ld_frag(Bc, wc * 64 + nf * 16 + lm, kc * 4 + quad);
#pragma unroll
        for (int mf = 0; mf < 2; ++mf)
#pragma unroll
          for (int nf = 0; nf < 4; ++nf)
            acc[mf][nf] = mfma16(af[mf], bf[nf], acc[mf][nf]);
      }
      if (it < 3) {
        asm volatile("s_waitcnt lgkmcnt(0)" ::: "memory");
        __builtin_amdgcn_sched_barrier(0);
        __builtin_amdgcn_s_barrier();
      }
    }
    int p0 = (n0 + wc * 64) >> 5;
#pragma unroll
    for (int j = 0; j < 2; ++j) {
      int gcol = (p0 + j) * 16 + lm;
      float bv = b1[gcol], bg = b1[1024 + gcol];
#pragma unroll
      for (int mf = 0; mf < 2; ++mf)
#pragma unroll
        for (int r = 0; r < 4; ++r) {
          int row = m0 + wr * 32 + mf * 16 + quad * 4 + r;
          float val = acc[mf][2 * j][r] + bv;
          float gate = acc[mf][2 * j + 1][r] + bg;
          float ge = 0.5f * gate * (1.0f + erff(gate * 0.70710678118654752440f));
          G[(size_t)row * IN1 + gcol] = f2b(val * ge);
        }
    }
    __syncthreads();  // LDS reuse hazard between reps
  }
}

// ---- row GEMM + residual + LN phase: 16x256, BK=64, T4 counted schedule -----
__device__ __forceinline__ void phase_rowln(
    const u16* __restrict__ A, int lda, const u16* __restrict__ BT, int K,
    const float* __restrict__ bias, float* __restrict__ X,
    const float* __restrict__ lng, const float* __restrict__ lnb,
    u16* __restrict__ Hout,
    const float* __restrict__ Wout, const float* __restrict__ bout,
    float* __restrict__ outp, u16* smem) {
  u16* Asb[2] = {smem, smem + 1024};
  u16* Bsb[2] = {smem + 2048, smem + 18432};
  int tid = threadIdx.x;
  int wave = tid >> 6, lane = tid & 63;
  int lm = lane & 15, quad = lane >> 4;
  int m0 = (int)blockIdx.x * 16;

  floatx4 acc[2];
#pragma unroll
  for (int nf = 0; nf < 2; ++nf)
#pragma unroll
    for (int r = 0; r < 4; ++r) acc[nf][r] = 0.0f;

  const u16* Ab = A + (size_t)m0 * lda;

  // early residual prefetch (oldest vmem ops; counted waits below account for them)
  float xres[2][4];
#pragma unroll
  for (int nf = 0; nf < 2; ++nf)
#pragma unroll
    for (int r = 0; r < 4; ++r)
      xres[nf][r] =
          X[(size_t)(m0 + quad * 4 + r) * DD + wave * 32 + nf * 16 + lm];

  auto stageA = [&](int k0, u16* dst) {
    if (tid < 128) {  // 128 slots (16 rows x 8 groups), waves 0-1: 1 load
      int sbase = wave * 64;
      int slot = sbase + lane;
      int row = slot >> 3;
      int kg = (slot & 7) ^ (row & 7);
      gload_lds16(Ab + (size_t)row * lda + k0 + kg * 8, dst + sbase * 8);
    }
  };
  auto stageB = [&](int k0, u16* dst) {
#pragma unroll
    for (int j = 0; j < 4; ++j) {  // 2048 slots / 512 thr: 4 loads/wave
      int sbase = j * 512 + wave * 64;
      int slot = sbase + lane;
      int row = slot >> 3;
      int kg = (slot & 7) ^ (row & 7);
      gload_lds16(BT + (size_t)row * K + k0 + kg * 8, dst + sbase * 8);
    }
  };

  stageA(0, Asb[0]);
  stageB(0, Bsb[0]);
  int iters = K >> 6;
#pragma unroll 1
  for (int it = 0; it < iters; ++it) {
    if (it + 1 < iters) {
      stageA((it + 1) * 64, Asb[(it + 1) & 1]);
      stageB((it + 1) * 64, Bsb[(it + 1) & 1]);
      // waves0-1 issue 5/stage, waves2-7 issue 4/stage
      if (wave < 2) asm volatile("s_waitcnt vmcnt(5)" ::: "memory");
      else          asm volatile("s_waitcnt vmcnt(4)" ::: "memory");
    } else {
      asm volatile("s_waitcnt vmcnt(0)" ::: "memory");
    }
    __builtin_amdgcn_s_barrier();
    __builtin_amdgcn_sched_barrier(0);
    const u16* Ac = Asb[it & 1];
    const u16* Bc = Bsb[it & 1];
#pragma unroll
    for (int kc = 0; kc < 2; ++kc) {
      short8 af = ld_frag(Ac, lm, kc * 4 + quad);
#pragma unroll
      for (int nf = 0; nf < 2; ++nf) {
        short8 bf = ld_frag(Bc, wave * 32 + nf * 16 + lm, kc * 4 + quad);
        acc[nf] = mfma16(af, bf, acc[nf]);
      }
    }
    asm volatile("s_waitcnt lgkmcnt(0)" ::: "memory");
    __builtin_amdgcn_sched_barrier(0);
    __builtin_amdgcn_s_barrier();
  }
  // epilogue: residual into X and LDS (xs = Bsb[0], 16 KB of 32 KB region)
  float* xs = (float*)Bsb[0];
#pragma unroll
  for (int nf = 0; nf < 2; ++nf) {
    int col = wave * 32 + nf * 16 + lm;
    float bv = bias ? bias[col] : 0.0f;
#pragma unroll
    for (int r = 0; r < 4; ++r) {
      int row = quad * 4 + r;
      float v = acc[nf][r] + bv + xres[nf][r];
      X[(size_t)(m0 + row) * DD + col] = v;
      xs[row * DD + col] = v;
    }
  }
  __syncthreads();
  float4 gg = *(const float4*)(lng + lane * 4);
  float4 bb = *(const float4*)(lnb + lane * 4);
#pragma unroll
  for (int rr = 0; rr < 2; ++rr) {
    int row = wave * 2 + rr;
    float4 v = *(const float4*)&xs[row * DD + lane * 4];
    float s = wave_sum(v.x + v.y + v.z + v.w);
    float mu = s * (1.0f / DD);
    float dx = v.x - mu, dy = v.y - mu, dz = v.z - mu, dw = v.w - mu;
    float ss = wave_sum(dx * dx + dy * dy + dz * dz + dw * dw);
    float rc = rsqrtf(ss * (1.0f / DD) + 1e-5f);
    float o0 = dx * rc * gg.x + bb.x;
    float o1 = dy * rc * gg.y + bb.y;
    float o2 = dz * rc * gg.z + bb.z;
    float o3 = dw * rc * gg.w + bb.w;
    ushort4v o4;
    o4[0] = f2b(o0); o4[1] = f2b(o1); o4[2] = f2b(o2); o4[3] = f2b(o3);
    *(ushort4v*)(Hout + (size_t)(m0 + row) * DD + lane * 4) = o4;
    if (Wout) {  // final layer: fused output projection (256 -> 2)
      int d0 = lane * 4;
      float s0 = o0 * Wout[d0 * 2] + o1 * Wout[(d0 + 1) * 2] +
                 o2 * Wout[(d0 + 2) * 2] + o3 * Wout[(d0 + 3) * 2];
      float s1 = o0 * Wout[d0 * 2 + 1] + o1 * Wout[(d0 + 1) * 2 + 1] +
                 o2 * Wout[(d0 + 2) * 2 + 1] + o3 * Wout[(d0 + 3) * 2 + 1];
      s0 = wave_sum(s0);
      s1 = wave_sum(s1);
      if (lane == 0) {
        outp[(size_t)(m0 + row) * 2 + 0] = s0 + bout[0];
        outp[(size_t)(m0 + row) * 2 + 1] = s1 + bout[1];
      }
    }
  }
  __syncthreads();
}

// ---- attention phase: flash, 128 q rows/block, 8 waves ----------------------
__device__ __forceinline__ void phase_attn(
    const u16* __restrict__ qk, const u16* __restrict__ vT,
    const int* __restrict__ mask_raw, u16* __restrict__ O, u16* smem) {
  u16* Ksb[2] = {smem, smem + 4096};
  u16* Vsb[2] = {smem + 8192, smem + 12288};
  u16* Ps = smem + 16384;                 // [8][16][72]
  float* madd = (float*)(smem + 25600);   // [64]

  const int tid = threadIdx.x, wave = tid >> 6, lane = tid & 63;
  const int lm = lane & 15, quad = lane >> 4;
  const int bid = blockIdx.x;
  const int qb = bid & 3, h = (bid >> 2) & 7, b = bid >> 5;
  const float slope = exp2f(-(float)(h + 1));

  int w0 = mask_raw[0];
  int mmode = (w0 == 1) ? 0 : ((w0 == 0x3f800000) ? 2 : 1);
  const int krow_base = b * LL;

  int ntv = 8;
#pragma unroll
  for (int t = 7; t >= 0; --t) {
    bool tv;
    int gi = krow_base + t * 64;
    if (mmode == 0) tv = mask_raw[gi] != 0;
    else if (mmode == 1) tv = ((const signed char*)mask_raw)[gi] != 0;
    else tv = ((const float*)mask_raw)[gi] != 0.0f;
    if (!tv) ntv = t;
  }

  const int q0 = qb * 128 + wave * 16;
  const int qg = b * LL + q0;
  const float qpos = (float)(q0 + lm);

  const u16* qp = qk + (size_t)(qg + lm) * 1024 + h * 64 + quad * 8;
  short8 qf0 = *(const short8*)qp;
  short8 qf1 = *(const short8*)(qp + 32);

  floatx4 oc[4];
#pragma unroll
  for (int nf = 0; nf < 4; ++nf)
#pragma unroll
    for (int r = 0; r < 4; ++r) oc[nf][r] = 0.0f;
  float mrow = -1e30f, lrow = 0.0f;

  const u16* kbase_p = qk + (size_t)krow_base * 1024 + 512 + h * 64;
  const u16* vbase = vT + (size_t)(b * 8 + h) * 64 * 512;

  stage512<512>(kbase_p, 1024, Ksb[0], tid);
  stage512<512>(vbase, 512, Vsb[0], tid);
  if (tid < 64) {
    int gi = krow_base + (ntv - 1) * 64 + tid;
    bool valid;
    if (mmode == 0) valid = mask_raw[gi] != 0;
    else if (mmode == 1) valid = ((const signed char*)mask_raw)[gi] != 0;
    else valid = ((const float*)mask_raw)[gi] != 0.0f;
    madd[tid] = valid ? 0.0f : -1e9f;
  }
  __syncthreads();  // madd visible; stage(0) drained

#pragma unroll 1
  for (int t = 0; t < ntv; ++t) {
    int k0 = t * 64;
    if (t + 1 < ntv) {
      stage512<512>(kbase_p + (size_t)(t + 1) * 64 * 1024, 1024,
                    Ksb[(t + 1) & 1], tid);
      stage512<512>(vbase + (t + 1) * 64, 512, Vsb[(t + 1) & 1], tid);
      asm volatile("s_waitcnt vmcnt(2)" ::: "memory");  // stage(t) landed
    } else {
      asm volatile("s_waitcnt vmcnt(0)" ::: "memory");
    }
    __builtin_amdgcn_s_barrier();
    __builtin_amdgcn_sched_barrier(0);
    const u16* Kc = Ksb[t & 1];
    const u16* Vc = Vsb[t & 1];
    bool bnd = (t == ntv - 1);

    float sc[4][4];
    float tmax = -3e38f;
#pragma unroll
    for (int nt = 0; nt < 4; ++nt) {
      floatx4 pc;
#pragma unroll
      for (int r = 0; r < 4; ++r) pc[r] = 0.0f;
      short8 kf0 = ld_frag(Kc, nt * 16 + lm, quad);
      short8 kf1 = ld_frag(Kc, nt * 16 + lm, 4 + quad);
      pc = mfma16(kf0, qf0, pc);
      pc = mfma16(kf1, qf1, pc);
      float kbase = (float)(k0 + nt * 16 + quad * 4);
#pragma unroll
      for (int r = 0; r < 4; ++r) {
        float s = pc[r] * 0.125f - slope * fabsf(qpos - (kbase + r));
        sc[nt][r] = s;
      }
      if (bnd) {
        float4 ma = *(const float4*)&madd[nt * 16 + quad * 4];
#pragma unroll
        for (int r = 0; r < 4; ++r) sc[nt][r] += ((const float*)&ma)[r];
      }
#pragma unroll
      for (int r = 0; r < 4; ++r) tmax = fmaxf(tmax, sc[nt][r]);
    }
    tmax = fmaxf(tmax, __shfl_xor(tmax, 16));
    tmax = fmaxf(tmax, __shfl_xor(tmax, 32));
    float nm = fmaxf(mrow, tmax);
    float alpha = __expf(mrow - nm);
    mrow = nm;
    float rsum = 0.0f;
#pragma unroll
    for (int nt = 0; nt < 4; ++nt)
#pragma unroll
      for (int r = 0; r < 4; ++r) {
        float p = __expf(sc[nt][r] - nm);
        sc[nt][r] = p;
        rsum += p;
      }
    rsum += __shfl_xor(rsum, 16);
    rsum += __shfl_xor(rsum, 32);
    lrow = lrow * alpha + rsum;
    float av[4];
#pragma unroll
    for (int r = 0; r < 4; ++r) av[r] = __shfl(alpha, quad * 4 + r);
#pragma unroll
    for (int nf = 0; nf < 4; ++nf)
#pragma unroll
      for (int r = 0; r < 4; ++r) oc[nf][r] *= av[r];
#pragma unroll
    for (int nt = 0; nt < 4; ++nt) {
      ushort4v p4;
#pragma unroll
      for (int r = 0; r < 4; ++r) p4[r] = f2b(sc[nt][r]);
      *(ushort4v*)&Ps[(wave * 16 + lm) * 72 + nt * 16 + quad * 4] = p4;
    }
#pragma unroll
    for (int kc = 0; kc < 2; ++kc) {
      short8 af = *(const short8*)&Ps[(wave * 16 + lm) * 72 + kc * 32 + quad * 8];
#pragma unroll
      for (int nf = 0; nf < 4; ++nf) {
        short8 bv = ld_frag(Vc, nf * 16 + lm, kc * 4 + quad);
        oc[nf] = mfma16(af, bv, oc[nf]);
      }
    }
    if (t + 2 < ntv) {  // compute(t) reads done before stage(t+2) writes
      asm volatile("s_waitcnt lgkmcnt(0)" ::: "memory");
      __builtin_amdgcn_sched_barrier(0);
      __builtin_amdgcn_s_barrier();
    }
  }
  float rl = 1.0f / lrow;
  float rv[4];
#pragma unroll
  for (int r = 0; r < 4; ++r) rv[r] = __shfl(rl, quad * 4 + r);
#pragma unroll
  for (int nf = 0; nf < 4; ++nf)
#pragma unroll
    for (int r = 0; r < 4; ++r) {
      int qq = qg + quad * 4 + r;
      O[(size_t)qq * HDH + h * 64 + nf * 16 + lm] = f2b(oc[nf][r] * rv[r]);
    }
}

// ---- the persistent layer-stack kernel --------------------------------------
__global__ __launch_bounds__(512, 4) void mega_kernel(
    u16* __restrict__ hb, const u16* __restrict__ wbuf,
    u16* __restrict__ qk, u16* __restrict__ vT,
    u16* __restrict__ obuf, u16* __restrict__ gbuf,
    float* __restrict__ x, const int* __restrict__ mask,
    const float* __restrict__ b1, const float* __restrict__ b2,
    const float* __restrict__ ln1g, const float* __restrict__ ln1b,
    const float* __restrict__ ln2g, const float* __restrict__ ln2b,
    const float* __restrict__ fng, const float* __restrict__ fnb,
    const float* __restrict__ Wout, const float* __restrict__ bout,
    float* __restrict__ out, unsigned* bar) {
  __shared__ __align__(16) u16 smem[34816];  // 68 KB
  unsigned syncno = 0;
#pragma unroll 1
  for (int l = 0; l < NLAYER; ++l) {
    const u16* wl = wbuf + (size_t)l * WBUF_LAYER;

    phase_qkv(hb, wl, qk, vT, smem);
    gsync(bar, syncno);

    phase_attn(qk, vT, mask, obuf, smem);
    gsync(bar, syncno);

    phase_rowln(obuf, HDH, wl + 393216, HDH, nullptr, x,
                ln2g + l * DD, ln2b + l * DD, hb,
                nullptr, nullptr, nullptr, smem);
    gsync(bar, syncno);

    phase_ffn1(hb, wl + 524288, b1 + (size_t)l * IN2, gbuf, smem);
    gsync(bar, syncno);

    const float* ng = (l < NLAYER - 1) ? (ln1g + (l + 1) * DD) : fng;
    const float* nb = (l < NLAYER - 1) ? (ln1b + (l + 1) * DD) : fnb;
    phase_rowln(gbuf, IN1, wl + 1048576, IN1, b2 + (size_t)l * DD, x, ng, nb, hb,
                (l == NLAYER - 1) ? Wout : nullptr,
                (l == NLAYER - 1) ? bout : nullptr,
                (l == NLAYER - 1) ? out : nullptr, smem);
    if (l + 1 < NLAYER) gsync(bar, syncno);
  }
}

extern "C" void kernel_launch(void* const* d_in, const int* in_sizes, int n_in,
                              void* d_out, int out_size, void* d_ws, size_t ws_size,
                              hipStream_t stream) {
  const int* seq = (const int*)d_in[0];
  const int* mask = (const int*)d_in[1];
  const float* emb = (const float*)d_in[2];
  const float* png = (const float*)d_in[3];
  const float* pnb = (const float*)d_in[4];
  const float* ln1g = (const float*)d_in[5];
  const float* ln1b = (const float*)d_in[6];
  const float* Wq = (const float*)d_in[7];
  const float* Wk = (const float*)d_in[8];
  const float* Wv = (const float*)d_in[9];
  const float* Wo = (const float*)d_in[10];
  const float* ln2g = (const float*)d_in[11];
  const float* ln2b = (const float*)d_in[12];
  const float* W1 = (const float*)d_in[13];
  const float* b1 = (const float*)d_in[14];
  const float* W2 = (const float*)d_in[15];
  const float* b2 = (const float*)d_in[16];
  const float* fng = (const float*)d_in[17];
  const float* fnb = (const float*)d_in[18];
  const float* Wout = (const float*)d_in[19];
  const float* bout = (const float*)d_in[20];
  float* out = (float*)d_out;

  uint8_t* wsb = (uint8_t*)d_ws;
  float* x = (float*)(wsb + 0);            //  4 MB
  u16* hb = (u16*)(wsb + 4194304);         //  2 MB
  u16* wbuf = (u16*)(wsb + 6291456);       // 40 MB (all layers)
  u16* qk = (u16*)(wsb + 48234496);        //  8 MB
  u16* vT = (u16*)(wsb + 56623104);        //  4 MB
  u16* obuf = (u16*)(wsb + 60817408);      //  4 MB
  u16* gbuf = (u16*)(wsb + 65011712);      //  8 MB
  unsigned* bar = (unsigned*)(wsb + 73400320);  // 2 u32 barrier state

  const int M = BB * LL;  // 4096

  prep_weights_kernel<<<16 * 1280, 256, 0, stream>>>(Wq, Wk, Wv, Wo, W1, W2, wbuf);
  embed_ln_kernel<<<M / 4, 256, 0, stream>>>(seq, emb, png, pnb, ln1g, ln1b, x, hb, bar);

  mega_kernel<<<256, 512, 0, stream>>>(
      hb, wbuf, qk, vT, obuf, gbuf, x, mask, b1, b2,
      ln1g, ln1b, ln2g, ln2b, fng, fnb, Wout, bout, out, bar);

  (void)in_sizes; (void)n_in; (void)out_size; (void)ws_size;
}

// Round 7
// 1124.116 us; speedup vs baseline: 3.3096x; 3.2462x over previous
//
#include <hip/hip_runtime.h>
#include <cstdint>
#include <cstddef>

// Problem constants
#define BB 8
#define LL 512
#define DD 256
#define HH 8
#define DHD 64
#define NLAYER 16
#define HDH 512   // H*DH
#define IN2 2048  // 2*INNER
#define IN1 1024  // INNER

typedef __attribute__((ext_vector_type(8))) short short8;     // 8 x bf16 (mfma A/B frag)
typedef __attribute__((ext_vector_type(4))) float floatx4;    // mfma C/D frag
typedef __attribute__((ext_vector_type(4))) unsigned short ushort4v;
typedef unsigned short u16;

__device__ __forceinline__ floatx4 mfma16(short8 a, short8 b, floatx4 c) {
  return __builtin_amdgcn_mfma_f32_16x16x32_bf16(a, b, c, 0, 0, 0);
}

__device__ __forceinline__ u16 f2b(float f) {
  union { float f; unsigned u; } x; x.f = f;
  unsigned u = x.u + 0x7fffu + ((x.u >> 16) & 1u);  // RNE
  return (u16)(u >> 16);
}

__device__ __forceinline__ float wave_sum(float s) {
#pragma unroll
  for (int off = 32; off; off >>= 1) s += __shfl_xor(s, off);
  return s;
}

// ---- async global->LDS (16B/lane), XOR-swizzled tiles (64-elem rows) ----------
__device__ __forceinline__ void gload_lds16(const u16* g, u16* l) {
  __builtin_amdgcn_global_load_lds((__attribute__((address_space(1))) void*)g,
                                   (__attribute__((address_space(3))) void*)l,
                                   16, 0, 0);
}

template <int NSLOTS, int NTHREADS = 256>  // NSLOTS = rows*8
__device__ __forceinline__ void stage_tile(const u16* __restrict__ g, int rowstride,
                                           u16* lds, int tid) {
  int wave = tid >> 6, lane = tid & 63;
#pragma unroll
  for (int j = 0; j < NSLOTS / NTHREADS; ++j) {
    int sbase = j * NTHREADS + wave * 64;   // wave-uniform LDS base (slots)
    int slot = sbase + lane;
    int row = slot >> 3;
    int kg = (slot & 7) ^ (row & 7);
    gload_lds16(g + (size_t)row * rowstride + kg * 8, lds + sbase * 8);
  }
}

__device__ __forceinline__ short8 ld_frag(const u16* T, int row, int kg) {
  return *(const short8*)&T[(row << 6) + (((kg ^ row) & 7) << 3)];
}

// ---- 128-elem-row variants (BK=128 tiles, 16 groups/row) ----------------------
__device__ __forceinline__ short8 ld_frag128(const u16* T, int row, int kg) {
  int pg = (kg & 8) | ((kg ^ row) & 7);
  return *(const short8*)&T[(row << 7) + (pg << 3)];
}

// ---------------- fused embed + prenorm-LN + layer0 ln1 ----------------
__device__ __forceinline__ float4 ln_math(const float* __restrict__ x,
                                          const float* __restrict__ g,
                                          const float* __restrict__ b, int t) {
  float4 v = *(const float4*)(x + t * 4);
  float s = wave_sum(v.x + v.y + v.z + v.w);
  float mu = s * (1.0f / DD);
  float dx = v.x - mu, dy = v.y - mu, dz = v.z - mu, dw = v.w - mu;
  float ss = wave_sum(dx * dx + dy * dy + dz * dz + dw * dw);
  float r = rsqrtf(ss * (1.0f / DD) + 1e-5f);
  float4 gg = *(const float4*)(g + t * 4);
  float4 bb = *(const float4*)(b + t * 4);
  float4 o;
  o.x = dx * r * gg.x + bb.x;
  o.y = dy * r * gg.y + bb.y;
  o.z = dz * r * gg.z + bb.z;
  o.w = dw * r * gg.w + bb.w;
  return o;
}

__global__ __launch_bounds__(256) void embed_ln_kernel(
    const int* __restrict__ seq, const float* __restrict__ emb,
    const float* __restrict__ png, const float* __restrict__ pnb,
    const float* __restrict__ g1, const float* __restrict__ b1,
    float* __restrict__ X, u16* __restrict__ H) {
  int row = blockIdx.x * 4 + (threadIdx.x >> 6), t = threadIdx.x & 63;
  int tok = seq[row];
  float4 o = ln_math(emb + (size_t)tok * DD, png, pnb, t);
  *(float4*)(X + (size_t)row * DD + t * 4) = o;
  float s = wave_sum(o.x + o.y + o.z + o.w);
  float mu = s * (1.0f / DD);
  float dx = o.x - mu, dy = o.y - mu, dz = o.z - mu, dw = o.w - mu;
  float ss = wave_sum(dx * dx + dy * dy + dz * dz + dw * dw);
  float r = rsqrtf(ss * (1.0f / DD) + 1e-5f);
  float4 gg = *(const float4*)(g1 + t * 4);
  float4 bb = *(const float4*)(b1 + t * 4);
  ushort4v o4;
  o4[0] = f2b(dx * r * gg.x + bb.x);
  o4[1] = f2b(dy * r * gg.y + bb.y);
  o4[2] = f2b(dz * r * gg.z + bb.z);
  o4[3] = f2b(dw * r * gg.w + bb.w);
  *(ushort4v*)(H + (size_t)row * DD + t * 4) = o4;
}

// ---------------- weight transpose+convert for ALL layers (one dispatch) ----------
#define WBUF_LAYER 1310720
__global__ __launch_bounds__(256) void prep_weights_kernel(
    const float* __restrict__ Wq, const float* __restrict__ Wk,
    const float* __restrict__ Wv, const float* __restrict__ Wo,
    const float* __restrict__ W1, const float* __restrict__ W2,
    u16* __restrict__ wbuf_all) {
  __shared__ float tile[32][33];
  int l = blockIdx.x / 1280;
  int bx = blockIdx.x % 1280;
  int tid = threadIdx.x;
  const float* wq = Wq + (size_t)l * DD * HDH;
  const float* wk = Wk + (size_t)l * DD * HDH;
  const float* wv = Wv + (size_t)l * DD * HDH;
  const float* wo = Wo + (size_t)l * HDH * DD;
  const float* w1 = W1 + (size_t)l * DD * IN2;
  const float* w2 = W2 + (size_t)l * IN1 * DD;
  u16* wbuf = wbuf_all + (size_t)l * WBUF_LAYER;

  const float* src; int srcld; u16* dst; int dstld; int dn0, k0, scol0;
  int packW1 = 0;
  if (bx < 384) {
    int t = bx; dn0 = (t % 48) * 32; k0 = (t / 48) * 32;
    scol0 = dn0 & 511;
    src = (dn0 < 512) ? wq : ((dn0 < 1024) ? wk : wv);
    srcld = 512; dst = wbuf; dstld = 256;
  } else if (bx < 512) {
    int t = bx - 384; dn0 = (t % 8) * 32; k0 = (t / 8) * 32; scol0 = dn0;
    src = wo; srcld = 256; dst = wbuf + 393216; dstld = 512;
  } else if (bx < 1024) {
    int t = bx - 512; dn0 = (t % 64) * 32; k0 = (t / 64) * 32; scol0 = dn0;
    src = w1; srcld = 2048; dst = wbuf + 524288; dstld = 256; packW1 = 1;
  } else {
    int t = bx - 1024; dn0 = (t % 8) * 32; k0 = (t / 8) * 32; scol0 = dn0;
    src = w2; srcld = 256; dst = wbuf + 1048576; dstld = 1024;
  }
  int r = tid >> 3, c4 = (tid & 7) * 4;
  float4 v = *(const float4*)&src[(size_t)(k0 + r) * srcld + scol0 + c4];
  tile[r][c4 + 0] = v.x; tile[r][c4 + 1] = v.y;
  tile[r][c4 + 2] = v.z; tile[r][c4 + 3] = v.w;
  __syncthreads();
  int n = tid >> 3, kk = (tid & 7) * 4;
  int drow = dn0 + n;
  if (packW1) {
    if (drow < 1024) drow = ((drow >> 4) << 5) | (drow & 15);
    else { int nn = drow - 1024; drow = (((nn >> 4) << 5) + 16) | (nn & 15); }
  }
  ushort4v o4;
  o4[0] = f2b(tile[kk + 0][n]); o4[1] = f2b(tile[kk + 1][n]);
  o4[2] = f2b(tile[kk + 2][n]); o4[3] = f2b(tile[kk + 3][n]);
  *(ushort4v*)&dst[(size_t)drow * dstld + k0 + kk] = o4;
}

// ---------------- QKV GEMM 128x96 (512 blocks; T4 counted-vmcnt dbuf) ----------
// 1D grid 512, XCD-chunked swizzle (T1): xcd = bid&7 owns m-panels [4*xcd, +4),
// all 16 n-tiles co-located on that XCD -> A panel fetched 1x (was 8x, once per
// XCD under round-robin); B panels 1x per XCD (fit in 4MB L2).
// Per-iter issue: 4 A-loads + 3 B-loads = 7/wave (uniform) -> vmcnt(7) mid-loop.
__global__ __launch_bounds__(256) void gemm_qkv(
    const u16* __restrict__ A, const u16* __restrict__ BT,
    u16* __restrict__ qk, u16* __restrict__ vT) {
  __shared__ __align__(16) u16 As[2][128 * 64];
  __shared__ __align__(16) u16 Bs[2][96 * 64];
  int tid = threadIdx.x;
  int wave = tid >> 6, lane = tid & 63;
  int lm = lane & 15, quad = lane >> 4;
  int wr = wave >> 1, wc = wave & 1;
  int bid = blockIdx.x;
  int idx = bid >> 3;
  int n0 = (idx & 15) * 96;
  int m0 = ((bid & 7) * 4 + (idx >> 4)) * 128;
  const u16* Ab = A + (size_t)m0 * DD;
  const u16* Bb = BT + (size_t)n0 * DD;

  floatx4 acc[4][3];
#pragma unroll
  for (int mf = 0; mf < 4; ++mf)
#pragma unroll
    for (int nf = 0; nf < 3; ++nf)
#pragma unroll
      for (int r = 0; r < 4; ++r) acc[mf][nf][r] = 0.0f;

  stage_tile<1024>(Ab, DD, As[0], tid);
  stage_tile<768>(Bb, DD, Bs[0], tid);
#pragma unroll
  for (int it = 0; it < 4; ++it) {
    if (it < 3) {
      stage_tile<1024>(Ab + (it + 1) * 64, DD, As[(it + 1) & 1], tid);
      stage_tile<768>(Bb + (it + 1) * 64, DD, Bs[(it + 1) & 1], tid);
      asm volatile("s_waitcnt vmcnt(7)" ::: "memory");   // stage(it) done; (it+1) in flight
    } else {
      asm volatile("s_waitcnt vmcnt(0)" ::: "memory");
    }
    __builtin_amdgcn_s_barrier();
    __builtin_amdgcn_sched_barrier(0);
    const u16* Ac = As[it & 1];
    const u16* Bc = Bs[it & 1];
#pragma unroll
    for (int kc = 0; kc < 2; ++kc) {
      short8 af[4], bf[3];
#pragma unroll
      for (int mf = 0; mf < 4; ++mf)
        af[mf] = ld_frag(Ac, wr * 64 + mf * 16 + lm, kc * 4 + quad);
#pragma unroll
      for (int nf = 0; nf < 3; ++nf)
        bf[nf] = ld_frag(Bc, wc * 48 + nf * 16 + lm, kc * 4 + quad);
#pragma unroll
      for (int mf = 0; mf < 4; ++mf)
#pragma unroll
        for (int nf = 0; nf < 3; ++nf)
          acc[mf][nf] = mfma16(af[mf], bf[nf], acc[mf][nf]);
    }
    if (it < 3) {
      asm volatile("s_waitcnt lgkmcnt(0)" ::: "memory");  // compute(it) reads done
      __builtin_amdgcn_sched_barrier(0);
      __builtin_amdgcn_s_barrier();                       // before stage(it+2) writes
    }
  }
#pragma unroll
  for (int mf = 0; mf < 4; ++mf)
#pragma unroll
    for (int nf = 0; nf < 3; ++nf) {
      int colf = n0 + wc * 48 + nf * 16;  // frag-uniform (1024 % 16 == 0)
      if (colf < 1024) {
#pragma unroll
        for (int r = 0; r < 4; ++r) {
          int row = m0 + wr * 64 + mf * 16 + quad * 4 + r;
          qk[(size_t)row * 1024 + colf + lm] = f2b(acc[mf][nf][r]);
        }
      } else {
        int token0 = m0 + wr * 64 + mf * 16 + quad * 4;
        int hd = colf + lm - 1024;
        int b = token0 >> 9, key = token0 & 511;
        ushort4v p4;
#pragma unroll
        for (int r = 0; r < 4; ++r) p4[r] = f2b(acc[mf][nf][r]);
        *(ushort4v*)&vT[((size_t)(b * 8 + (hd >> 6)) * 64 + (hd & 63)) * 512 + key] = p4;
      }
    }
}

// ---------------- W1 GEMM 128x128 + fused GeGLU (T4 counted-vmcnt dbuf) ----------
// 1D grid 512, XCD-chunked swizzle (T1): same mapping as gemm_qkv.
// Per-iter issue: 4 A-loads + 4 B-loads = 8/wave (uniform) -> vmcnt(8) mid-loop.
__global__ __launch_bounds__(256) void gemm_ffn1(
    const u16* __restrict__ A, const u16* __restrict__ BTp,
    const float* __restrict__ b1, u16* __restrict__ G) {
  __shared__ __align__(16) u16 As[2][128 * 64];
  __shared__ __align__(16) u16 Bs[2][128 * 64];
  int tid = threadIdx.x;
  int wave = tid >> 6, lane = tid & 63;
  int lm = lane & 15, quad = lane >> 4;
  int wr = wave >> 1, wc = wave & 1;
  int bid = blockIdx.x;
  int idx = bid >> 3;
  int n0 = (idx & 15) * 128;
  int m0 = ((bid & 7) * 4 + (idx >> 4)) * 128;
  const u16* Ab = A + (size_t)m0 * DD;
  const u16* Bb = BTp + (size_t)n0 * DD;

  floatx4 acc[4][4];
#pragma unroll
  for (int mf = 0; mf < 4; ++mf)
#pragma unroll
    for (int nf = 0; nf < 4; ++nf)
#pragma unroll
      for (int r = 0; r < 4; ++r) acc[mf][nf][r] = 0.0f;

  stage_tile<1024>(Ab, DD, As[0], tid);
  stage_tile<1024>(Bb, DD, Bs[0], tid);
#pragma unroll
  for (int it = 0; it < 4; ++it) {
    if (it < 3) {
      stage_tile<1024>(Ab + (it + 1) * 64, DD, As[(it + 1) & 1], tid);
      stage_tile<1024>(Bb + (it + 1) * 64, DD, Bs[(it + 1) & 1], tid);
      asm volatile("s_waitcnt vmcnt(8)" ::: "memory");   // stage(it) done; (it+1) in flight
    } else {
      asm volatile("s_waitcnt vmcnt(0)" ::: "memory");
    }
    __builtin_amdgcn_s_barrier();
    __builtin_amdgcn_sched_barrier(0);
    const u16* Ac = As[it & 1];
    const u16* Bc = Bs[it & 1];
#pragma unroll
    for (int kc = 0; kc < 2; ++kc) {
      short8 af[4], bf[4];
#pragma unroll
      for (int mf = 0; mf < 4; ++mf)
        af[mf] = ld_frag(Ac, wr * 64 + mf * 16 + lm, kc * 4 + quad);
#pragma unroll
      for (int nf = 0; nf < 4; ++nf)
        bf[nf] = ld_frag(Bc, wc * 64 + nf * 16 + lm, kc * 4 + quad);
#pragma unroll
      for (int mf = 0; mf < 4; ++mf)
#pragma unroll
        for (int nf = 0; nf < 4; ++nf)
          acc[mf][nf] = mfma16(af[mf], bf[nf], acc[mf][nf]);
    }
    if (it < 3) {
      asm volatile("s_waitcnt lgkmcnt(0)" ::: "memory");  // compute(it) reads done
      __builtin_amdgcn_sched_barrier(0);
      __builtin_amdgcn_s_barrier();                       // before stage(it+2) writes
    }
  }
  int p0 = (n0 + wc * 64) >> 5;
#pragma unroll
  for (int j = 0; j < 2; ++j) {
    int gcol = (p0 + j) * 16 + lm;
    float bv = b1[gcol], bg = b1[1024 + gcol];
#pragma unroll
    for (int mf = 0; mf < 4; ++mf)
#pragma unroll
      for (int r = 0; r < 4; ++r) {
        int row = m0 + wr * 64 + mf * 16 + quad * 4 + r;
        float val = acc[mf][2 * j][r] + bv;
        float gate = acc[mf][2 * j + 1][r] + bg;
        float ge = 0.5f * gate * (1.0f + erff(gate * 0.70710678118654752440f));
        G[(size_t)row * IN1 + gcol] = f2b(val * ge);
      }
  }
}

// ---------------- GEMM (16x256 full-row, BK=128) + residual + LN (+outproj) ----
// 512 threads = 8 waves; wave w owns cols [w*32, +32). BK=128 dbuf.
// T4 counted-vmcnt schedule + early X-residual prefetch.
__global__ __launch_bounds__(512) void gemm_row_ln(
    const u16* __restrict__ A, int lda, const u16* __restrict__ BT, int K,
    const float* __restrict__ bias, float* __restrict__ X,
    const float* __restrict__ lng, const float* __restrict__ lnb,
    u16* __restrict__ Hout,
    const float* __restrict__ Wout, const float* __restrict__ bout,
    float* __restrict__ outp) {
  __shared__ __align__(16) u16 As[2][16 * 128];    //  8 KB
  __shared__ __align__(16) u16 Bs[2][256 * 128];   // 128 KB
  int tid = threadIdx.x;
  int wave = tid >> 6, lane = tid & 63;
  int lm = lane & 15, quad = lane >> 4;
  int m0 = blockIdx.x * 16;

  floatx4 acc[2];
#pragma unroll
  for (int nf = 0; nf < 2; ++nf)
#pragma unroll
    for (int r = 0; r < 4; ++r) acc[nf][r] = 0.0f;

  const u16* Ab = A + (size_t)m0 * lda;

  // early residual prefetch (epilogue operand; hides latency under K-loop)
  float xres[2][4];
#pragma unroll
  for (int nf = 0; nf < 2; ++nf)
#pragma unroll
    for (int r = 0; r < 4; ++r)
      xres[nf][r] =
          X[(size_t)(m0 + quad * 4 + r) * DD + wave * 32 + nf * 16 + lm];

  // stage helpers (BK=128, 16 groups/row)
  auto stageA = [&](int k0, u16* dst) {
    if (wave < 4) {  // 256 slots
      int sbase = wave * 64;
      int slot = sbase + lane;
      int row = slot >> 4, pg = slot & 15;
      int kg = (pg & 8) | ((pg ^ row) & 7);
      gload_lds16(Ab + (size_t)row * lda + k0 + kg * 8, dst + sbase * 8);
    }
  };
  auto stageB = [&](int k0, u16* dst) {
#pragma unroll
    for (int j = 0; j < 8; ++j) {  // 4096 slots / 512 thr
      int sbase = j * 512 + wave * 64;
      int slot = sbase + lane;
      int row = slot >> 4, pg = slot & 15;
      int kg = (pg & 8) | ((pg ^ row) & 7);
      gload_lds16(BT + (size_t)row * K + k0 + kg * 8, dst + sbase * 8);
    }
  };

  stageA(0, As[0]);
  stageB(0, Bs[0]);
  int iters = K >> 7;
  for (int it = 0; it < iters; ++it) {
    if (it + 1 < iters) {
      stageA((it + 1) * 128, As[(it + 1) & 1]);
      stageB((it + 1) * 128, Bs[(it + 1) & 1]);
      // wait for stage(it) only; stage(it+1)'s loads remain in flight
      if (wave < 4) asm volatile("s_waitcnt vmcnt(9)" ::: "memory");
      else          asm volatile("s_waitcnt vmcnt(8)" ::: "memory");
    } else {
      asm volatile("s_waitcnt vmcnt(0)" ::: "memory");
    }
    __builtin_amdgcn_s_barrier();
    __builtin_amdgcn_sched_barrier(0);
    const u16* Ac = As[it & 1];
    const u16* Bc = Bs[it & 1];
#pragma unroll
    for (int kc = 0; kc < 4; ++kc) {
      short8 af = ld_frag128(Ac, lm, kc * 4 + quad);
#pragma unroll
      for (int nf = 0; nf < 2; ++nf) {
        short8 bf = ld_frag128(Bc, wave * 32 + nf * 16 + lm, kc * 4 + quad);
        acc[nf] = mfma16(af, bf, acc[nf]);
      }
    }
    asm volatile("s_waitcnt lgkmcnt(0)" ::: "memory");
    __builtin_amdgcn_sched_barrier(0);
    __builtin_amdgcn_s_barrier();
  }
  // epilogue: residual into X and LDS (xs = Bs[0], 16 KB)
  float* xs = (float*)Bs[0];
#pragma unroll
  for (int nf = 0; nf < 2; ++nf) {
    int col = wave * 32 + nf * 16 + lm;
    float bv = bias ? bias[col] : 0.0f;
#pragma unroll
    for (int r = 0; r < 4; ++r) {
      int row = quad * 4 + r;
      float v = acc[nf][r] + bv + xres[nf][r];
      X[(size_t)(m0 + row) * DD + col] = v;
      xs[row * DD + col] = v;
    }
  }
  __syncthreads();
  float4 gg = *(const float4*)(lng + lane * 4);
  float4 bb = *(const float4*)(lnb + lane * 4);
#pragma unroll
  for (int rr = 0; rr < 2; ++rr) {
    int row = wave * 2 + rr;
    float4 v = *(const float4*)&xs[row * DD + lane * 4];
    float s = wave_sum(v.x + v.y + v.z + v.w);
    float mu = s * (1.0f / DD);
    float dx = v.x - mu, dy = v.y - mu, dz = v.z - mu, dw = v.w - mu;
    float ss = wave_sum(dx * dx + dy * dy + dz * dz + dw * dw);
    float rc = rsqrtf(ss * (1.0f / DD) + 1e-5f);
    float o0 = dx * rc * gg.x + bb.x;
    float o1 = dy * rc * gg.y + bb.y;
    float o2 = dz * rc * gg.z + bb.z;
    float o3 = dw * rc * gg.w + bb.w;
    ushort4v o4;
    o4[0] = f2b(o0); o4[1] = f2b(o1); o4[2] = f2b(o2); o4[3] = f2b(o3);
    *(ushort4v*)(Hout + (size_t)(m0 + row) * DD + lane * 4) = o4;
    if (Wout) {  // final layer: fused output projection (256 -> 2)
      int d0 = lane * 4;
      float s0 = o0 * Wout[d0 * 2] + o1 * Wout[(d0 + 1) * 2] +
                 o2 * Wout[(d0 + 2) * 2] + o3 * Wout[(d0 + 3) * 2];
      float s1 = o0 * Wout[d0 * 2 + 1] + o1 * Wout[(d0 + 1) * 2 + 1] +
                 o2 * Wout[(d0 + 2) * 2 + 1] + o3 * Wout[(d0 + 3) * 2 + 1];
      s0 = wave_sum(s0);
      s1 = wave_sum(s1);
      if (lane == 0) {
        outp[(size_t)(m0 + row) * 2 + 0] = s0 + bout[0];
        outp[(size_t)(m0 + row) * 2 + 1] = s1 + bout[1];
      }
    }
  }
}

// ---------------- MFMA flash attention v7 (128 q/block, 8 waves) ----------
// 1D grid 256, XCD-chunked swizzle (T1): xcd = bid&7 owns 8 (b,h) pairs with
// all 4 q-blocks co-located -> K/V tiles fetched 1x per XCD (was 4x).
// T4 counted-vmcnt: mid-loop vmcnt(2); barrier #2 only when stage(t+2) exists.
__global__ __launch_bounds__(512) void attn_mfma_kernel(
    const u16* __restrict__ qk, const u16* __restrict__ vT,
    const int* __restrict__ mask_raw, u16* __restrict__ O) {
  __shared__ __align__(16) u16 Ks[2][64 * 64];
  __shared__ __align__(16) u16 Vs[2][64 * 64];
  __shared__ __align__(16) u16 Ps[8][16][72];
  __shared__ __align__(16) float madd[64];

  const int tid = threadIdx.x, wave = tid >> 6, lane = tid & 63;
  const int lm = lane & 15, quad = lane >> 4;
  const int bid = blockIdx.x;
  const int idx = bid >> 3;
  const int bh = (bid & 7) * 8 + (idx & 7);
  const int qb = idx >> 3;
  const int b = bh >> 3, h = bh & 7;
  const float slope = exp2f(-(float)(h + 1));

  int w0 = mask_raw[0];
  int mmode = (w0 == 1) ? 0 : ((w0 == 0x3f800000) ? 2 : 1);
  const int krow_base = b * LL;

  // valid tile count (mask monotone; len>=256 => ntv>=4)
  int ntv = 8;
#pragma unroll
  for (int t = 7; t >= 0; --t) {
    bool tv;
    int gi = krow_base + t * 64;
    if (mmode == 0) tv = mask_raw[gi] != 0;
    else if (mmode == 1) tv = ((const signed char*)mask_raw)[gi] != 0;
    else tv = ((const float*)mask_raw)[gi] != 0.0f;
    if (!tv) ntv = t;
  }

  const int q0 = qb * 128 + wave * 16;
  const int qg = b * LL + q0;
  const float qpos = (float)(q0 + lm);

  const u16* qp = qk + (size_t)(qg + lm) * 1024 + h * 64 + quad * 8;
  short8 qf0 = *(const short8*)qp;
  short8 qf1 = *(const short8*)(qp + 32);

  floatx4 oc[4];
#pragma unroll
  for (int nf = 0; nf < 4; ++nf)
#pragma unroll
    for (int r = 0; r < 4; ++r) oc[nf][r] = 0.0f;
  float mrow = -1e30f, lrow = 0.0f;

  const u16* kbase_p = qk + (size_t)krow_base * 1024 + 512 + h * 64;
  const u16* vbase = vT + (size_t)(b * 8 + h) * 64 * 512;

  stage_tile<512, 512>(kbase_p, 1024, Ks[0], tid);
  stage_tile<512, 512>(vbase, 512, Vs[0], tid);
  if (tid < 64) {
    int gi = krow_base + (ntv - 1) * 64 + tid;
    bool valid;
    if (mmode == 0) valid = mask_raw[gi] != 0;
    else if (mmode == 1) valid = ((const signed char*)mask_raw)[gi] != 0;
    else valid = ((const float*)mask_raw)[gi] != 0.0f;
    madd[tid] = valid ? 0.0f : -1e9f;
  }
  __syncthreads();  // madd visible; stage(0) drained (prologue only)

  for (int t = 0; t < ntv; ++t) {
    int k0 = t * 64;
    if (t + 1 < ntv) {
      stage_tile<512, 512>(kbase_p + (size_t)(t + 1) * 64 * 1024, 1024,
                           Ks[(t + 1) & 1], tid);
      stage_tile<512, 512>(vbase + (t + 1) * 64, 512, Vs[(t + 1) & 1], tid);
      asm volatile("s_waitcnt vmcnt(2)" ::: "memory");  // stage(t) landed
    } else {
      asm volatile("s_waitcnt vmcnt(0)" ::: "memory");
    }
    __builtin_amdgcn_s_barrier();
    __builtin_amdgcn_sched_barrier(0);
    const u16* Kc = Ks[t & 1];
    const u16* Vc = Vs[t & 1];
    bool bnd = (t == ntv - 1);

    float sc[4][4];
    float tmax = -3e38f;
#pragma unroll
    for (int nt = 0; nt < 4; ++nt) {
      floatx4 pc;
#pragma unroll
      for (int r = 0; r < 4; ++r) pc[r] = 0.0f;
      short8 kf0 = ld_frag(Kc, nt * 16 + lm, quad);
      short8 kf1 = ld_frag(Kc, nt * 16 + lm, 4 + quad);
      pc = mfma16(kf0, qf0, pc);
      pc = mfma16(kf1, qf1, pc);
      float kbase = (float)(k0 + nt * 16 + quad * 4);
#pragma unroll
      for (int r = 0; r < 4; ++r) {
        float s = pc[r] * 0.125f - slope * fabsf(qpos - (kbase + r));
        sc[nt][r] = s;
      }
      if (bnd) {
        float4 ma = *(const float4*)&madd[nt * 16 + quad * 4];
#pragma unroll
        for (int r = 0; r < 4; ++r) sc[nt][r] += ((const float*)&ma)[r];
      }
#pragma unroll
      for (int r = 0; r < 4; ++r) tmax = fmaxf(tmax, sc[nt][r]);
    }
    tmax = fmaxf(tmax, __shfl_xor(tmax, 16));
    tmax = fmaxf(tmax, __shfl_xor(tmax, 32));
    float nm = fmaxf(mrow, tmax);
    float alpha = __expf(mrow - nm);
    mrow = nm;
    float rsum = 0.0f;
#pragma unroll
    for (int nt = 0; nt < 4; ++nt)
#pragma unroll
      for (int r = 0; r < 4; ++r) {
        float p = __expf(sc[nt][r] - nm);
        sc[nt][r] = p;
        rsum += p;
      }
    rsum += __shfl_xor(rsum, 16);
    rsum += __shfl_xor(rsum, 32);
    lrow = lrow * alpha + rsum;
    float av[4];
#pragma unroll
    for (int r = 0; r < 4; ++r) av[r] = __shfl(alpha, quad * 4 + r);
#pragma unroll
    for (int nf = 0; nf < 4; ++nf)
#pragma unroll
      for (int r = 0; r < 4; ++r) oc[nf][r] *= av[r];
#pragma unroll
    for (int nt = 0; nt < 4; ++nt) {
      ushort4v p4;
#pragma unroll
      for (int r = 0; r < 4; ++r) p4[r] = f2b(sc[nt][r]);
      *(ushort4v*)&Ps[wave][lm][nt * 16 + quad * 4] = p4;
    }
#pragma unroll
    for (int kc = 0; kc < 2; ++kc) {
      short8 af = *(const short8*)&Ps[wave][lm][kc * 32 + quad * 8];
#pragma unroll
      for (int nf = 0; nf < 4; ++nf) {
        short8 bv = ld_frag(Vc, nf * 16 + lm, kc * 4 + quad);
        oc[nf] = mfma16(af, bv, oc[nf]);
      }
    }
    if (t + 2 < ntv) {  // compute(t) reads done before stage(t+2) writes
      asm volatile("s_waitcnt lgkmcnt(0)" ::: "memory");
      __builtin_amdgcn_sched_barrier(0);
      __builtin_amdgcn_s_barrier();
    }
  }
  float rl = 1.0f / lrow;
  float rv[4];
#pragma unroll
  for (int r = 0; r < 4; ++r) rv[r] = __shfl(rl, quad * 4 + r);
#pragma unroll
  for (int nf = 0; nf < 4; ++nf)
#pragma unroll
    for (int r = 0; r < 4; ++r) {
      int qq = qg + quad * 4 + r;
      O[(size_t)qq * HDH + h * 64 + nf * 16 + lm] = f2b(oc[nf][r] * rv[r]);
    }
}

extern "C" void kernel_launch(void* const* d_in, const int* in_sizes, int n_in,
                              void* d_out, int out_size, void* d_ws, size_t ws_size,
                              hipStream_t stream) {
  const int* seq = (const int*)d_in[0];
  const int* mask = (const int*)d_in[1];
  const float* emb = (const float*)d_in[2];
  const float* png = (const float*)d_in[3];
  const float* pnb = (const float*)d_in[4];
  const float* ln1g = (const float*)d_in[5];
  const float* ln1b = (const float*)d_in[6];
  const float* Wq = (const float*)d_in[7];
  const float* Wk = (const float*)d_in[8];
  const float* Wv = (const float*)d_in[9];
  const float* Wo = (const float*)d_in[10];
  const float* ln2g = (const float*)d_in[11];
  const float* ln2b = (const float*)d_in[12];
  const float* W1 = (const float*)d_in[13];
  const float* b1 = (const float*)d_in[14];
  const float* W2 = (const float*)d_in[15];
  const float* b2 = (const float*)d_in[16];
  const float* fng = (const float*)d_in[17];
  const float* fnb = (const float*)d_in[18];
  const float* Wout = (const float*)d_in[19];
  const float* bout = (const float*)d_in[20];
  float* out = (float*)d_out;

  uint8_t* wsb = (uint8_t*)d_ws;
  float* x = (float*)(wsb + 0);            //  4 MB
  u16* hb = (u16*)(wsb + 4194304);         //  2 MB
  u16* wbuf = (u16*)(wsb + 6291456);       // 40 MB (all layers)
  u16* qk = (u16*)(wsb + 48234496);        //  8 MB
  u16* vT = (u16*)(wsb + 56623104);        //  4 MB
  u16* obuf = (u16*)(wsb + 60817408);      //  4 MB
  u16* gbuf = (u16*)(wsb + 65011712);      //  8 MB

  const int M = BB * LL;  // 4096

  prep_weights_kernel<<<16 * 1280, 256, 0, stream>>>(Wq, Wk, Wv, Wo, W1, W2, wbuf);
  embed_ln_kernel<<<M / 4, 256, 0, stream>>>(seq, emb, png, pnb, ln1g, ln1b, x, hb);

  for (int l = 0; l < NLAYER; ++l) {
    u16* wl = wbuf + (size_t)l * WBUF_LAYER;

    gemm_qkv<<<512, 256, 0, stream>>>(hb, wl, qk, vT);

    attn_mfma_kernel<<<256, 512, 0, stream>>>(qk, vT, mask, obuf);

    // x += o @ Wo ; hb = ln2(x)
    gemm_row_ln<<<M / 16, 512, 0, stream>>>(
        obuf, HDH, wl + 393216, HDH, nullptr, x,
        ln2g + l * DD, ln2b + l * DD, hb, nullptr, nullptr, nullptr);

    // g = geglu(hb @ W1 + b1)
    gemm_ffn1<<<512, 256, 0, stream>>>(
        hb, wl + 524288, b1 + (size_t)l * IN2, gbuf);

    // x += g @ W2 + b2 ; hb = ln1(next) or final LN (+fused outproj on last)
    const float* ng = (l < NLAYER - 1) ? (ln1g + (l + 1) * DD) : fng;
    const float* nb = (l < NLAYER - 1) ? (ln1b + (l + 1) * DD) : fnb;
    const float* wo_p = (l == NLAYER - 1) ? Wout : nullptr;
    const float* bo_p = (l == NLAYER - 1) ? bout : nullptr;
    float* out_p = (l == NLAYER - 1) ? out : nullptr;
    gemm_row_ln<<<M / 16, 512, 0, stream>>>(
        gbuf, IN1, wl + 1048576, IN1, b2 + (size_t)l * DD, x, ng, nb, hb,
        wo_p, bo_p, out_p);
  }

  (void)in_sizes; (void)n_in; (void)out_size; (void)ws_size;
}